// Round 7
// baseline (233.901 us; speedup 1.0000x reference)
//
#include <hip/hip_runtime.h>
#include <math.h>

// Problem constants
#define HWX   6400   // 80*80
#define WID   80
#define HGT   80
#define CMID  128
#define CIN   256
#define COUT  256

// Workspace layout (float/dword offsets)
#define WS_BN   0            // s1[128] b1[128] s2[128] b2[128] s3[256] b3[256] = 1024
#define WS_Y2   1024         // (8,6400,128) bf16 NHWC = 3,276,800 dwords
#define WS_Z2   3277824      // (8,6400,128) bf16 NHWC = 3,276,800 dwords
#define WS_WPK  6554624      // dcn_w prepacked A-frags: 73,728 dwords
#define WS_WPO  6628352      // off_w prepacked A-frags: 18,432 dwords
#define WS_WP1  6646784      // cv1_w prepacked A-frags: 16,384 dwords
#define WS_WP3  6663168      // cv3_w prepacked A-frags: 16,384 dwords

typedef float floatx16 __attribute__((ext_vector_type(16)));
typedef short shortx8  __attribute__((ext_vector_type(8)));
typedef float floatx2  __attribute__((ext_vector_type(2)));

union U8 { uint32_t u[4]; shortx8 s; };

__device__ __forceinline__ float silu_f(float t){ return t / (1.f + __expf(-t)); }
__device__ __forceinline__ uint32_t f2bf(float f){           // RNE fp32->bf16 (cold paths)
    uint32_t u = __float_as_uint(f);
    return (u + 0x7fffu + ((u >> 16) & 1u)) >> 16;
}
// unpack bf16x2 dword -> float2 (lo, hi)
__device__ __forceinline__ floatx2 up2(uint32_t u){
    floatx2 r; r.x = __uint_as_float(u << 16); r.y = __uint_as_float(u & 0xffff0000u); return r;
}
// pack float2 -> bf16x2 dword (round-half-up: +0x8000 then take high halves via v_perm)
__device__ __forceinline__ uint32_t pk2(floatx2 v){
    return __builtin_amdgcn_perm(__float_as_uint(v.y) + 0x8000u,
                                 __float_as_uint(v.x) + 0x8000u, 0x07060302u);
}
__device__ __forceinline__ uint32_t pk2f(float a, float b){ floatx2 v; v.x=a; v.y=b; return pk2(v); }

// ---------------- prep: BN fold + MFMA weight prepacks ----------------
// A-frag convention (verified): lane's oc = g*32 + (lane&31);
// k-index c = s*16 + (lane>>5)*8 + 2j (+1 in hi half of dword j).
__global__ __launch_bounds__(256) void k0_prep(
    const float* __restrict__ dcn_w, const float* __restrict__ off_w,
    const float* __restrict__ cv1_w, const float* __restrict__ cv3_w,
    const float* __restrict__ g1, const float* __restrict__ b1, const float* __restrict__ m1, const float* __restrict__ v1,
    const float* __restrict__ g2, const float* __restrict__ b2, const float* __restrict__ m2, const float* __restrict__ v2,
    const float* __restrict__ dcn_b,
    const float* __restrict__ g3, const float* __restrict__ b3, const float* __restrict__ m3, const float* __restrict__ v3,
    uint32_t* __restrict__ wpk, uint32_t* __restrict__ wpo,
    uint32_t* __restrict__ wp1, uint32_t* __restrict__ wp3, float* __restrict__ bnw)
{
    int i = blockIdx.x * 256 + threadIdx.x;
    if (i < 4*9*8*256) {                   // dcn_w: ((g*9+tap)*8+s)*256 + lane*4 + j
        int j = i & 3, lane = (i >> 2) & 63, s = (i >> 8) & 7;
        int r2 = i >> 11; int tap = r2 % 9, g = r2 / 9;
        int oc = g*32 + (lane & 31);
        int c  = s*16 + ((lane >> 5) << 3) + 2*j;
        wpk[i] = f2bf(dcn_w[(oc*128 + c)*9 + tap]) | (f2bf(dcn_w[(oc*128 + c + 1)*9 + tap]) << 16);
    }
    if (i < 9*8*256) {                     // off_w (27 oc pad 32): (tap*8+s)*256 + lane*4 + j
        int j = i & 3, lane = (i >> 2) & 63, s = (i >> 8) & 7, tap = i >> 11;
        int oc = lane & 31;
        int c  = s*16 + ((lane >> 5) << 3) + 2*j;
        float lo = (oc < 27) ? off_w[(oc*128 + c)*9 + tap] : 0.f;
        float hi = (oc < 27) ? off_w[(oc*128 + c + 1)*9 + tap] : 0.f;
        wpo[i] = f2bf(lo) | (f2bf(hi) << 16);
    }
    if (i < 4*16*256) {                    // cv1_w (128x256): (g*16+s)*256 + lane*4 + j
        int j = i & 3, lane = (i >> 2) & 63, s = (i >> 8) & 15, g = i >> 12;
        int oc = g*32 + (lane & 31);
        int c  = s*16 + ((lane >> 5) << 3) + 2*j;
        wp1[i] = f2bf(cv1_w[oc*256 + c]) | (f2bf(cv1_w[oc*256 + c + 1]) << 16);
    }
    if (i < 8*8*256) {                     // cv3_w (256x128): (g*8+s)*256 + lane*4 + j
        int j = i & 3, lane = (i >> 2) & 63, s = (i >> 8) & 7, g = i >> 11;
        int oc = g*32 + (lane & 31);
        int c  = s*16 + ((lane >> 5) << 3) + 2*j;
        wp3[i] = f2bf(cv3_w[oc*128 + c]) | (f2bf(cv3_w[oc*128 + c + 1]) << 16);
    }
    if (i < 128) {
        float inv = g1[i] * rsqrtf(v1[i] + 1e-5f);
        bnw[i] = inv; bnw[128+i] = b1[i] - m1[i]*inv;
    } else if (i < 256) {
        int j = i - 128;
        float inv = g2[j] * rsqrtf(v2[j] + 1e-5f);
        bnw[256+j] = inv; bnw[384+j] = b2[j] - m2[j]*inv + inv*dcn_b[j];  // fold dcn bias
    } else if (i < 512) {
        int j = i - 256;
        float inv = g3[j] * rsqrtf(v3[j] + 1e-5f);
        bnw[512+j] = inv; bnw[768+j] = b3[j] - m3[j]*inv;
    }
}

// ---------------- k1: conv1x1 (256->128, MFMA) + BN1 + SiLU -> Y2 bf16 NHWC ----------------
#define K1PAD 68
__global__ __launch_bounds__(256) void k1_cv1(
    const float* __restrict__ x, const uint32_t* __restrict__ wp1,
    const float* __restrict__ bn, uint32_t* __restrict__ y2)
{
    __shared__ __align__(16) uint32_t L[64*66];  // staging [0..16*68); epilogue transpose [64][66]
    int blk = blockIdx.x;                  // 800
    int b = blk / 100, pix0 = (blk % 100) * 64;
    int t = threadIdx.x;
    int lane = t & 63, w = t >> 6;
    int pixl = lane & 31, bhalf = lane >> 5;
    floatx16 acc0 = {}, acc1 = {};
    const float* xb = x + (size_t)b*CIN*HWX + pix0;
    const uint32_t* wpg = wp1 + (size_t)(w*16)*256 + lane*4;

    int r2 = t >> 4, c4 = (t & 15) * 4;    // staging: thread loads ch pair (2*r2,2*r2+1), 4 pix
    for (int kk = 0; kk < 256; kk += 32) {
        float4 a0 = *(const float4*)(xb + (size_t)(kk + 2*r2)*HWX + c4);
        float4 a1 = *(const float4*)(xb + (size_t)(kk + 2*r2 + 1)*HWX + c4);
        uint4 q;
        q.x = pk2f(a0.x, a1.x);
        q.y = pk2f(a0.y, a1.y);
        q.z = pk2f(a0.z, a1.z);
        q.w = pk2f(a0.w, a1.w);
        __syncthreads();                   // prev iter's frag reads done
        *(uint4*)&L[r2*K1PAD + c4] = q;
        __syncthreads();
        #pragma unroll
        for (int sl = 0; sl < 2; sl++) {
            int s = (kk >> 4) + sl;
            U8 a, b0, b1;
            const uint32_t* as = wpg + s*256;
            a.u[0]=as[0]; a.u[1]=as[1]; a.u[2]=as[2]; a.u[3]=as[3];
            int row = sl*8 + bhalf*4;
            #pragma unroll
            for (int j = 0; j < 4; j++) b0.u[j] = L[(row+j)*K1PAD + pixl];
            #pragma unroll
            for (int j = 0; j < 4; j++) b1.u[j] = L[(row+j)*K1PAD + 32 + pixl];
            acc0 = __builtin_amdgcn_mfma_f32_32x32x16_bf16(a.s, b0.s, acc0, 0, 0, 0);
            acc1 = __builtin_amdgcn_mfma_f32_32x32x16_bf16(a.s, b1.s, acc1, 0, 0, 0);
        }
    }
    __syncthreads();
    #pragma unroll
    for (int r = 0; r < 16; r += 2) {
        int oc = w*32 + (r & 3) + 8*(r >> 2) + 4*bhalf;      // even; pair (oc, oc+1)
        float s0 = bn[oc],   be0 = bn[128+oc];
        float s1 = bn[oc+1], be1 = bn[128+oc+1];
        uint32_t d0 = pk2f(silu_f(acc0[r]*s0+be0), silu_f(acc0[r+1]*s1+be1));
        uint32_t d1 = pk2f(silu_f(acc1[r]*s0+be0), silu_f(acc1[r+1]*s1+be1));
        int oc2 = oc >> 1;
        L[pixl*66 + oc2]        = d0;
        L[(32+pixl)*66 + oc2]   = d1;
    }
    __syncthreads();
    uint32_t* y2b = y2 + (size_t)b*HWX*64 + (size_t)pix0*64;
    int q2 = t & 31, p0 = t >> 5;
    #pragma unroll
    for (int pp = 0; pp < 8; pp++) {
        int pix = p0 + pp*8;
        uint2 v = make_uint2(L[pix*66 + q2*2], L[pix*66 + q2*2 + 1]);
        *(uint2*)(y2b + (size_t)pix*64 + q2*2) = v;
    }
}

// ---------------- k3: fused offset-conv + deformable conv (MFMA bf16) ----------------
// Round-0 structure + XCD batch swizzle (verified: FETCH 41->8 MB, 97->81.7us).
// This round: tap+1 gather ISSUE moved BEFORE the barrier (T14 issue-early /
// consume-late). Gathers read only yb (global RO) + sidx9/swgt9 (LDS, frozen
// since phase B) -> pure reorder, no race/numerics change. Barrier-wait +
// MFMA section now both cover the L2 gather latency.
#define S2R 68
__global__ __launch_bounds__(256) void k3_dcn(
    const uint32_t* __restrict__ y2, const uint32_t* __restrict__ wpo,
    const float* __restrict__ ob,
    const uint32_t* __restrict__ wpk, const float* __restrict__ bn, uint32_t* __restrict__ z2)
{
    __shared__ __align__(16) uint32_t S2[2][32*S2R];   // 17408 B (phase A reuses as 4x1024 fp32)
    __shared__ __align__(16) int   sidx9[9*32*4];      // 4608 B
    __shared__ __align__(16) float swgt9[9*32*4];      // 4608 B
    int i0 = blockIdx.x;                   // 1600
    int blk = (i0 & 7) * 200 + (i0 >> 3);  // bijective; XCD (i0%8) -> batch (i0&7)
    int b = blk / 200, pix0 = (blk % 200) * 32;
    int t = threadIdx.x;
    int lane = t & 63, w = t >> 6;
    int pixl = lane & 31, bhalf = lane >> 5;
    const uint32_t* yb = y2 + (size_t)b*HWX*64;
    floatx16 acc = {};
    int c4 = lane & 31, pixoff = lane >> 5;
    float* LF = (float*)&S2[0][0];

    // ---- phase A: offset-conv pred partials (wave w: taps 2w..2w+1, wave3: 6..8) ----
    {
        floatx16 accp = {};
        int tap0 = (w < 3) ? w*2 : 6;
        int ntap = (w < 3) ? 2 : 3;
        int p = pix0 + pixl;
        int h = p / WID, xw = p % WID;
        for (int tt = 0; tt < ntap; tt++) {
            int tap = tap0 + tt;
            int gh = h + tap/3 - 1, gx = xw + tap%3 - 1;
            bool valid = (gh >= 0) && (gh < HGT) && (gx >= 0) && (gx < WID);
            const uint32_t* pp2 = yb + (size_t)(gh*WID + gx)*64 + bhalf*4;
            const uint32_t* ap = wpo + (size_t)(tap*8)*256 + lane*4;
            #pragma unroll
            for (int s = 0; s < 8; s++) {
                U8 a, bf;
                const uint32_t* as = ap + s*256;
                a.u[0]=as[0]; a.u[1]=as[1]; a.u[2]=as[2]; a.u[3]=as[3];
                if (valid) {
                    uint4 q = *(const uint4*)(pp2 + s*8);
                    bf.u[0]=q.x; bf.u[1]=q.y; bf.u[2]=q.z; bf.u[3]=q.w;
                } else {
                    bf.u[0]=0u; bf.u[1]=0u; bf.u[2]=0u; bf.u[3]=0u;
                }
                accp = __builtin_amdgcn_mfma_f32_32x32x16_bf16(a.s, bf.s, accp, 0, 0, 0);
            }
        }
        #pragma unroll
        for (int r = 0; r < 16; r++) {
            int oc = (r & 3) + 8*(r >> 2) + 4*bhalf;
            LF[w*1024 + oc*32 + pixl] = accp[r];
        }
    }
    __syncthreads();
    // reduce 4 partials + bias; sigmoid mask channels; result in LF[oc*32+px]
    #pragma unroll
    for (int k = 0; k < 4; k++) {
        int e = t + 256*k;
        int oc = e >> 5;
        float v = LF[e] + LF[1024+e] + LF[2048+e] + LF[3072+e];
        if (oc < 27) {
            v += ob[oc];
            if (oc >= 18) v = 1.f/(1.f+__expf(-v));
        }
        LF[e] = v;
    }
    __syncthreads();

    // ---- phase B: bilinear params for all 9 taps (pred from LDS) ----
    for (int it = t; it < 288; it += 256) {
        int tap = it >> 5, px = it & 31;
        int pix = pix0 + px;
        int h = pix / WID, wq = pix % WID;
        float dy = LF[(2*tap)*32 + px];
        float dx = LF[(2*tap+1)*32 + px];
        float mk = LF[(18+tap)*32 + px];
        float pyf = (float)(h - 1 + tap/3) + dy;
        float pxf = (float)(wq - 1 + tap%3) + dx;
        float y0f = floorf(pyf), x0f = floorf(pxf);
        float wy1 = pyf - y0f, wx1 = pxf - x0f;
        int iy0 = (int)y0f, ix0 = (int)x0f;
        int iy1 = iy0 + 1,  ix1 = ix0 + 1;
        float vy0 = (iy0 >= 0 && iy0 < HGT) ? 1.f : 0.f;
        float vy1 = (iy1 >= 0 && iy1 < HGT) ? 1.f : 0.f;
        float vx0 = (ix0 >= 0 && ix0 < WID) ? 1.f : 0.f;
        float vx1 = (ix1 >= 0 && ix1 < WID) ? 1.f : 0.f;
        int cy0 = min(max(iy0,0),HGT-1), cy1 = min(max(iy1,0),HGT-1);
        int cx0 = min(max(ix0,0),WID-1), cx1 = min(max(ix1,0),WID-1);
        int base = (tap*32 + px)*4;
        sidx9[base+0] = cy0*WID+cx0; sidx9[base+1] = cy0*WID+cx1;
        sidx9[base+2] = cy1*WID+cx0; sidx9[base+3] = cy1*WID+cx1;
        swgt9[base+0] = (1.f-wy1)*(1.f-wx1)*mk*vy0*vx0;
        swgt9[base+1] = (1.f-wy1)*wx1*mk*vy0*vx1;
        swgt9[base+2] = wy1*(1.f-wx1)*mk*vy1*vx0;
        swgt9[base+3] = wy1*wx1*mk*vy1*vx1;
    }
    __syncthreads();

    // ---- phase C: main dcn loop ----
    uint2  u[4][4];      // [pass][corner] gathered channel data (this lane's 4 ch)
    float4 W[4];         // [pass] bilinear weights
    uint2  samp[4];      // [pass] packed bf16x2 x2 sampled output

    // prologue gather+compute for tap 0
    #pragma unroll
    for (int p = 0; p < 4; p++) {
        int pix = w*8 + p*2 + pixoff;
        int base = (0*32 + pix)*4;
        int4 si = *(const int4*)&sidx9[base];
        W[p] = *(const float4*)&swgt9[base];
        u[p][0] = *(const uint2*)(yb + (size_t)si.x*64 + c4*2);
        u[p][1] = *(const uint2*)(yb + (size_t)si.y*64 + c4*2);
        u[p][2] = *(const uint2*)(yb + (size_t)si.z*64 + c4*2);
        u[p][3] = *(const uint2*)(yb + (size_t)si.w*64 + c4*2);
    }
    #pragma unroll
    for (int p = 0; p < 4; p++) {
        floatx2 W0, W1, W2, W3;
        W0.x = W0.y = W[p].x; W1.x = W1.y = W[p].y;
        W2.x = W2.y = W[p].z; W3.x = W3.y = W[p].w;
        floatx2 aX = up2(u[p][0].x) * W0;
        aX = __builtin_elementwise_fma(up2(u[p][1].x), W1, aX);
        aX = __builtin_elementwise_fma(up2(u[p][2].x), W2, aX);
        aX = __builtin_elementwise_fma(up2(u[p][3].x), W3, aX);
        floatx2 aY = up2(u[p][0].y) * W0;
        aY = __builtin_elementwise_fma(up2(u[p][1].y), W1, aY);
        aY = __builtin_elementwise_fma(up2(u[p][2].y), W2, aY);
        aY = __builtin_elementwise_fma(up2(u[p][3].y), W3, aY);
        samp[p].x = pk2(aX); samp[p].y = pk2(aY);
    }

    #pragma unroll
    for (int tap = 0; tap < 9; tap++) {
        uint32_t* S = &S2[tap & 1][0];
        #pragma unroll
        for (int p = 0; p < 4; p++) {
            int pix = w*8 + p*2 + pixoff;
            *(uint2*)&S[pix*S2R + c4*2] = samp[p];
        }
        if (tap < 8) {                     // issue tap+1 gathers BEFORE the barrier
            #pragma unroll
            for (int p = 0; p < 4; p++) {
                int pix = w*8 + p*2 + pixoff;
                int base = ((tap+1)*32 + pix)*4;
                int4 si = *(const int4*)&sidx9[base];
                W[p] = *(const float4*)&swgt9[base];
                u[p][0] = *(const uint2*)(yb + (size_t)si.x*64 + c4*2);
                u[p][1] = *(const uint2*)(yb + (size_t)si.y*64 + c4*2);
                u[p][2] = *(const uint2*)(yb + (size_t)si.z*64 + c4*2);
                u[p][3] = *(const uint2*)(yb + (size_t)si.w*64 + c4*2);
            }
        }
        __syncthreads();
        const uint32_t* wp = wpk + (size_t)((w*9 + tap)*8)*256 + lane*4;
        #pragma unroll
        for (int s = 0; s < 8; s++) {
            U8 a, bf;
            const uint32_t* wps = wp + s*256;
            a.u[0] = wps[0]; a.u[1] = wps[1]; a.u[2] = wps[2]; a.u[3] = wps[3];
            uint4 q = *(const uint4*)&S[pixl*S2R + s*8 + bhalf*4];
            bf.u[0]=q.x; bf.u[1]=q.y; bf.u[2]=q.z; bf.u[3]=q.w;
            acc = __builtin_amdgcn_mfma_f32_32x32x16_bf16(a.s, bf.s, acc, 0, 0, 0);
        }
        if (tap < 8) {
            #pragma unroll
            for (int p = 0; p < 4; p++) {
                floatx2 W0, W1, W2, W3;
                W0.x = W0.y = W[p].x; W1.x = W1.y = W[p].y;
                W2.x = W2.y = W[p].z; W3.x = W3.y = W[p].w;
                floatx2 aX = up2(u[p][0].x) * W0;
                aX = __builtin_elementwise_fma(up2(u[p][1].x), W1, aX);
                aX = __builtin_elementwise_fma(up2(u[p][2].x), W2, aX);
                aX = __builtin_elementwise_fma(up2(u[p][3].x), W3, aX);
                floatx2 aY = up2(u[p][0].y) * W0;
                aY = __builtin_elementwise_fma(up2(u[p][1].y), W1, aY);
                aY = __builtin_elementwise_fma(up2(u[p][2].y), W2, aY);
                aY = __builtin_elementwise_fma(up2(u[p][3].y), W3, aY);
                samp[p].x = pk2(aX); samp[p].y = pk2(aY);
            }
        }
    }
    // epilogue: BN2+SiLU into S2[1] (tap 8 consumed S2[0])
    uint32_t* SE = &S2[1][0];
    #pragma unroll
    for (int r = 0; r < 16; r += 2) {
        int oc = w*32 + (r & 3) + 8*(r >> 2) + 4*bhalf;
        float s0 = bn[256+oc],   be0 = bn[384+oc];
        float s1 = bn[256+oc+1], be1 = bn[384+oc+1];
        SE[pixl*S2R + (oc >> 1)] = pk2f(silu_f(acc[r]*s0+be0), silu_f(acc[r+1]*s1+be1));
    }
    __syncthreads();
    uint32_t* z2b = z2 + (size_t)b*HWX*64 + (size_t)pix0*64;
    int q2 = t & 31, p0 = t >> 5;
    #pragma unroll
    for (int pp = 0; pp < 4; pp++) {
        int pix = p0 + pp*8;
        uint2 v = *(const uint2*)&SE[pix*S2R + q2*2];
        *(uint2*)(z2b + (size_t)pix*64 + q2*2) = v;
    }
}

// ---------------- k4: conv1x1 (128->256, MFMA) + BN3 + SiLU + residual ----------------
// Reverted to round-0 version (no LDS, no swizzle): the LDS-transpose epilogue
// round coincided with a ~11us rest-of-pipeline regression (34.8KB LDS caps
// k4 at 4 blocks/CU vs unlimited). A/B via total time this round.
__global__ __launch_bounds__(256) void k4_cv3(
    const uint32_t* __restrict__ z2, const uint32_t* __restrict__ wp3,
    const float* __restrict__ bn, const float* __restrict__ x, float* __restrict__ out)
{
    int blk = blockIdx.x;                  // 1600
    int half = blk & 1, blk2 = blk >> 1;
    int b = blk2 / 100, pix0 = (blk2 % 100) * 64;
    int t = threadIdx.x;
    int lane = t & 63, w = t >> 6;
    int pixl = lane & 31, bhalf = lane >> 5;
    int g = half*4 + w;
    floatx16 acc0 = {}, acc1 = {};
    const uint32_t* zb = z2 + (size_t)b*HWX*64 + (size_t)pix0*64;
    const uint32_t* wpg = wp3 + (size_t)(g*8)*256 + lane*4;

    #pragma unroll
    for (int s = 0; s < 8; s++) {
        U8 a, b0, b1;
        const uint32_t* as = wpg + s*256;
        a.u[0]=as[0]; a.u[1]=as[1]; a.u[2]=as[2]; a.u[3]=as[3];
        uint4 q0 = *(const uint4*)(zb + (size_t)pixl*64 + s*8 + bhalf*4);
        uint4 q1 = *(const uint4*)(zb + (size_t)(32+pixl)*64 + s*8 + bhalf*4);
        b0.u[0]=q0.x; b0.u[1]=q0.y; b0.u[2]=q0.z; b0.u[3]=q0.w;
        b1.u[0]=q1.x; b1.u[1]=q1.y; b1.u[2]=q1.z; b1.u[3]=q1.w;
        acc0 = __builtin_amdgcn_mfma_f32_32x32x16_bf16(a.s, b0.s, acc0, 0, 0, 0);
        acc1 = __builtin_amdgcn_mfma_f32_32x32x16_bf16(a.s, b1.s, acc1, 0, 0, 0);
    }
    const float* xb = x + (size_t)b*COUT*HWX + pix0;
    float* ob = out + (size_t)b*COUT*HWX + pix0;
    #pragma unroll
    for (int r = 0; r < 16; r++) {
        int oc = g*32 + (r & 3) + 8*(r >> 2) + 4*bhalf;
        float sc = bn[512+oc], be = bn[768+oc];
        float v0 = silu_f(acc0[r]*sc+be) + xb[(size_t)oc*HWX + pixl];
        float v1 = silu_f(acc1[r]*sc+be) + xb[(size_t)oc*HWX + 32 + pixl];
        ob[(size_t)oc*HWX + pixl]      = v0;
        ob[(size_t)oc*HWX + 32 + pixl] = v1;
    }
}

extern "C" void kernel_launch(void* const* d_in, const int* in_sizes, int n_in,
                              void* d_out, int out_size, void* d_ws, size_t ws_size,
                              hipStream_t stream) {
    const float* x     = (const float*)d_in[0];
    const float* cv1_w = (const float*)d_in[1];
    const float* bn1_g = (const float*)d_in[2];
    const float* bn1_b = (const float*)d_in[3];
    const float* bn1_m = (const float*)d_in[4];
    const float* bn1_v = (const float*)d_in[5];
    const float* off_w = (const float*)d_in[6];
    const float* off_b = (const float*)d_in[7];
    const float* dcn_w = (const float*)d_in[8];
    const float* dcn_b = (const float*)d_in[9];
    const float* bn2_g = (const float*)d_in[10];
    const float* bn2_b = (const float*)d_in[11];
    const float* bn2_m = (const float*)d_in[12];
    const float* bn2_v = (const float*)d_in[13];
    const float* cv3_w = (const float*)d_in[14];
    const float* bn3_g = (const float*)d_in[15];
    const float* bn3_b = (const float*)d_in[16];
    const float* bn3_m = (const float*)d_in[17];
    const float* bn3_v = (const float*)d_in[18];

    float* ws   = (float*)d_ws;
    float*    BN   = ws + WS_BN;
    uint32_t* Y2   = (uint32_t*)(ws + WS_Y2);
    uint32_t* Z2   = (uint32_t*)(ws + WS_Z2);
    uint32_t* WPK  = (uint32_t*)(ws + WS_WPK);
    uint32_t* WPO  = (uint32_t*)(ws + WS_WPO);
    uint32_t* WP1  = (uint32_t*)(ws + WS_WP1);
    uint32_t* WP3  = (uint32_t*)(ws + WS_WP3);

    hipLaunchKernelGGL(k0_prep, dim3(288), dim3(256), 0, stream,
        dcn_w, off_w, cv1_w, cv3_w,
        bn1_g, bn1_b, bn1_m, bn1_v,
        bn2_g, bn2_b, bn2_m, bn2_v, dcn_b,
        bn3_g, bn3_b, bn3_m, bn3_v, WPK, WPO, WP1, WP3, BN);
    hipLaunchKernelGGL(k1_cv1, dim3(800), dim3(256), 0, stream, x, WP1, BN, Y2);
    hipLaunchKernelGGL(k3_dcn, dim3(1600), dim3(256), 0, stream, Y2, WPO, off_b, WPK, BN, Z2);
    hipLaunchKernelGGL(k4_cv3, dim3(1600), dim3(256), 0, stream, Z2, WP3, BN, x, (float*)d_out);
}

// Round 8
// 232.368 us; speedup vs baseline: 1.0066x; 1.0066x over previous
//
#include <hip/hip_runtime.h>
#include <math.h>

// Problem constants
#define HWX   6400   // 80*80
#define WID   80
#define HGT   80
#define CMID  128
#define CIN   256
#define COUT  256

// Workspace layout (float/dword offsets)
#define WS_BN   0            // s1[128] b1[128] s2[128] b2[128] s3[256] b3[256] = 1024
#define WS_Y2   1024         // (8,6400,128) bf16 NHWC = 3,276,800 dwords
#define WS_Z2   3277824      // (8,6400,128) bf16 NHWC = 3,276,800 dwords
#define WS_WPK  6554624      // dcn_w prepacked A-frags: 73,728 dwords
#define WS_WPO  6628352      // off_w prepacked A-frags: 18,432 dwords
#define WS_WP1  6646784      // cv1_w prepacked A-frags: 16,384 dwords
#define WS_WP3  6663168      // cv3_w prepacked A-frags: 16,384 dwords

typedef float floatx16 __attribute__((ext_vector_type(16)));
typedef short shortx8  __attribute__((ext_vector_type(8)));
typedef float floatx2  __attribute__((ext_vector_type(2)));

union U8 { uint32_t u[4]; shortx8 s; };

__device__ __forceinline__ float silu_f(float t){ return t / (1.f + __expf(-t)); }
__device__ __forceinline__ uint32_t f2bf(float f){           // RNE fp32->bf16 (cold paths)
    uint32_t u = __float_as_uint(f);
    return (u + 0x7fffu + ((u >> 16) & 1u)) >> 16;
}
// unpack bf16x2 dword -> float2 (lo, hi)
__device__ __forceinline__ floatx2 up2(uint32_t u){
    floatx2 r; r.x = __uint_as_float(u << 16); r.y = __uint_as_float(u & 0xffff0000u); return r;
}
// pack float2 -> bf16x2 dword (round-half-up: +0x8000 then take high halves via v_perm)
__device__ __forceinline__ uint32_t pk2(floatx2 v){
    return __builtin_amdgcn_perm(__float_as_uint(v.y) + 0x8000u,
                                 __float_as_uint(v.x) + 0x8000u, 0x07060302u);
}
__device__ __forceinline__ uint32_t pk2f(float a, float b){ floatx2 v; v.x=a; v.y=b; return pk2(v); }

// ---------------- prep: BN fold + MFMA weight prepacks ----------------
// A-frag convention (verified): lane's oc = g*32 + (lane&31);
// k-index c = s*16 + (lane>>5)*8 + 2j (+1 in hi half of dword j).
__global__ __launch_bounds__(256) void k0_prep(
    const float* __restrict__ dcn_w, const float* __restrict__ off_w,
    const float* __restrict__ cv1_w, const float* __restrict__ cv3_w,
    const float* __restrict__ g1, const float* __restrict__ b1, const float* __restrict__ m1, const float* __restrict__ v1,
    const float* __restrict__ g2, const float* __restrict__ b2, const float* __restrict__ m2, const float* __restrict__ v2,
    const float* __restrict__ dcn_b,
    const float* __restrict__ g3, const float* __restrict__ b3, const float* __restrict__ m3, const float* __restrict__ v3,
    uint32_t* __restrict__ wpk, uint32_t* __restrict__ wpo,
    uint32_t* __restrict__ wp1, uint32_t* __restrict__ wp3, float* __restrict__ bnw)
{
    int i = blockIdx.x * 256 + threadIdx.x;
    if (i < 4*9*8*256) {                   // dcn_w: ((g*9+tap)*8+s)*256 + lane*4 + j
        int j = i & 3, lane = (i >> 2) & 63, s = (i >> 8) & 7;
        int r2 = i >> 11; int tap = r2 % 9, g = r2 / 9;
        int oc = g*32 + (lane & 31);
        int c  = s*16 + ((lane >> 5) << 3) + 2*j;
        wpk[i] = f2bf(dcn_w[(oc*128 + c)*9 + tap]) | (f2bf(dcn_w[(oc*128 + c + 1)*9 + tap]) << 16);
    }
    if (i < 9*8*256) {                     // off_w (27 oc pad 32): (tap*8+s)*256 + lane*4 + j
        int j = i & 3, lane = (i >> 2) & 63, s = (i >> 8) & 7, tap = i >> 11;
        int oc = lane & 31;
        int c  = s*16 + ((lane >> 5) << 3) + 2*j;
        float lo = (oc < 27) ? off_w[(oc*128 + c)*9 + tap] : 0.f;
        float hi = (oc < 27) ? off_w[(oc*128 + c + 1)*9 + tap] : 0.f;
        wpo[i] = f2bf(lo) | (f2bf(hi) << 16);
    }
    if (i < 4*16*256) {                    // cv1_w (128x256): (g*16+s)*256 + lane*4 + j
        int j = i & 3, lane = (i >> 2) & 63, s = (i >> 8) & 15, g = i >> 12;
        int oc = g*32 + (lane & 31);
        int c  = s*16 + ((lane >> 5) << 3) + 2*j;
        wp1[i] = f2bf(cv1_w[oc*256 + c]) | (f2bf(cv1_w[oc*256 + c + 1]) << 16);
    }
    if (i < 8*8*256) {                     // cv3_w (256x128): (g*8+s)*256 + lane*4 + j
        int j = i & 3, lane = (i >> 2) & 63, s = (i >> 8) & 7, g = i >> 11;
        int oc = g*32 + (lane & 31);
        int c  = s*16 + ((lane >> 5) << 3) + 2*j;
        wp3[i] = f2bf(cv3_w[oc*128 + c]) | (f2bf(cv3_w[oc*128 + c + 1]) << 16);
    }
    if (i < 128) {
        float inv = g1[i] * rsqrtf(v1[i] + 1e-5f);
        bnw[i] = inv; bnw[128+i] = b1[i] - m1[i]*inv;
    } else if (i < 256) {
        int j = i - 128;
        float inv = g2[j] * rsqrtf(v2[j] + 1e-5f);
        bnw[256+j] = inv; bnw[384+j] = b2[j] - m2[j]*inv + inv*dcn_b[j];  // fold dcn bias
    } else if (i < 512) {
        int j = i - 256;
        float inv = g3[j] * rsqrtf(v3[j] + 1e-5f);
        bnw[512+j] = inv; bnw[768+j] = b3[j] - m3[j]*inv;
    }
}

// ---------------- k1: conv1x1 (256->128, MFMA) + BN1 + SiLU -> Y2 bf16 NHWC ----------------
// Batch->XCD swizzle: batch b's Y2 slice (3.28 MB) is written through XCD b's
// L2, where k3 (same affinity) will read it.
#define K1PAD 68
__global__ __launch_bounds__(256) void k1_cv1(
    const float* __restrict__ x, const uint32_t* __restrict__ wp1,
    const float* __restrict__ bn, uint32_t* __restrict__ y2)
{
    __shared__ __align__(16) uint32_t L[64*66];  // staging [0..16*68); epilogue transpose [64][66]
    int i0 = blockIdx.x;                   // 800
    int blk = (i0 & 7) * 100 + (i0 >> 3);  // bijective; XCD (i0%8) -> batch (i0&7)
    int b = blk / 100, pix0 = (blk % 100) * 64;
    int t = threadIdx.x;
    int lane = t & 63, w = t >> 6;
    int pixl = lane & 31, bhalf = lane >> 5;
    floatx16 acc0 = {}, acc1 = {};
    const float* xb = x + (size_t)b*CIN*HWX + pix0;
    const uint32_t* wpg = wp1 + (size_t)(w*16)*256 + lane*4;

    int r2 = t >> 4, c4 = (t & 15) * 4;    // staging: thread loads ch pair (2*r2,2*r2+1), 4 pix
    for (int kk = 0; kk < 256; kk += 32) {
        float4 a0 = *(const float4*)(xb + (size_t)(kk + 2*r2)*HWX + c4);
        float4 a1 = *(const float4*)(xb + (size_t)(kk + 2*r2 + 1)*HWX + c4);
        uint4 q;
        q.x = pk2f(a0.x, a1.x);
        q.y = pk2f(a0.y, a1.y);
        q.z = pk2f(a0.z, a1.z);
        q.w = pk2f(a0.w, a1.w);
        __syncthreads();                   // prev iter's frag reads done
        *(uint4*)&L[r2*K1PAD + c4] = q;
        __syncthreads();
        #pragma unroll
        for (int sl = 0; sl < 2; sl++) {
            int s = (kk >> 4) + sl;
            U8 a, b0, b1;
            const uint32_t* as = wpg + s*256;
            a.u[0]=as[0]; a.u[1]=as[1]; a.u[2]=as[2]; a.u[3]=as[3];
            int row = sl*8 + bhalf*4;
            #pragma unroll
            for (int j = 0; j < 4; j++) b0.u[j] = L[(row+j)*K1PAD + pixl];
            #pragma unroll
            for (int j = 0; j < 4; j++) b1.u[j] = L[(row+j)*K1PAD + 32 + pixl];
            acc0 = __builtin_amdgcn_mfma_f32_32x32x16_bf16(a.s, b0.s, acc0, 0, 0, 0);
            acc1 = __builtin_amdgcn_mfma_f32_32x32x16_bf16(a.s, b1.s, acc1, 0, 0, 0);
        }
    }
    __syncthreads();
    #pragma unroll
    for (int r = 0; r < 16; r += 2) {
        int oc = w*32 + (r & 3) + 8*(r >> 2) + 4*bhalf;      // even; pair (oc, oc+1)
        float s0 = bn[oc],   be0 = bn[128+oc];
        float s1 = bn[oc+1], be1 = bn[128+oc+1];
        uint32_t d0 = pk2f(silu_f(acc0[r]*s0+be0), silu_f(acc0[r+1]*s1+be1));
        uint32_t d1 = pk2f(silu_f(acc1[r]*s0+be0), silu_f(acc1[r+1]*s1+be1));
        int oc2 = oc >> 1;
        L[pixl*66 + oc2]        = d0;
        L[(32+pixl)*66 + oc2]   = d1;
    }
    __syncthreads();
    uint32_t* y2b = y2 + (size_t)b*HWX*64 + (size_t)pix0*64;
    int q2 = t & 31, p0 = t >> 5;
    #pragma unroll
    for (int pp = 0; pp < 8; pp++) {
        int pix = p0 + pp*8;
        uint2 v = make_uint2(L[pix*66 + q2*2], L[pix*66 + q2*2 + 1]);
        *(uint2*)(y2b + (size_t)pix*64 + q2*2) = v;
    }
}

// ---------------- k3: fused offset-conv + deformable conv (MFMA bf16) ----------------
// EXACT round-5 version (verified 81.7us, FETCH 8 MB): gathers issued AFTER the
// barrier. Round 7's pre-barrier hoist REGRESSED 33% in cycles: __syncthreads
// lowers to s_waitcnt vmcnt(0)+s_barrier, so pre-barrier gathers get DRAINED at
// the barrier instead of overlapping the MFMA section. Do not hoist VMEM above
// __syncthreads.
#define S2R 68
__global__ __launch_bounds__(256) void k3_dcn(
    const uint32_t* __restrict__ y2, const uint32_t* __restrict__ wpo,
    const float* __restrict__ ob,
    const uint32_t* __restrict__ wpk, const float* __restrict__ bn, uint32_t* __restrict__ z2)
{
    __shared__ __align__(16) uint32_t S2[2][32*S2R];   // 17408 B (phase A reuses as 4x1024 fp32)
    __shared__ __align__(16) int   sidx9[9*32*4];      // 4608 B
    __shared__ __align__(16) float swgt9[9*32*4];      // 4608 B
    int i0 = blockIdx.x;                   // 1600
    int blk = (i0 & 7) * 200 + (i0 >> 3);  // bijective; XCD (i0%8) -> batch (i0&7)
    int b = blk / 200, pix0 = (blk % 200) * 32;
    int t = threadIdx.x;
    int lane = t & 63, w = t >> 6;
    int pixl = lane & 31, bhalf = lane >> 5;
    const uint32_t* yb = y2 + (size_t)b*HWX*64;
    floatx16 acc = {};
    int c4 = lane & 31, pixoff = lane >> 5;
    float* LF = (float*)&S2[0][0];

    // ---- phase A: offset-conv pred partials (wave w: taps 2w..2w+1, wave3: 6..8) ----
    {
        floatx16 accp = {};
        int tap0 = (w < 3) ? w*2 : 6;
        int ntap = (w < 3) ? 2 : 3;
        int p = pix0 + pixl;
        int h = p / WID, xw = p % WID;
        for (int tt = 0; tt < ntap; tt++) {
            int tap = tap0 + tt;
            int gh = h + tap/3 - 1, gx = xw + tap%3 - 1;
            bool valid = (gh >= 0) && (gh < HGT) && (gx >= 0) && (gx < WID);
            const uint32_t* pp2 = yb + (size_t)(gh*WID + gx)*64 + bhalf*4;
            const uint32_t* ap = wpo + (size_t)(tap*8)*256 + lane*4;
            #pragma unroll
            for (int s = 0; s < 8; s++) {
                U8 a, bf;
                const uint32_t* as = ap + s*256;
                a.u[0]=as[0]; a.u[1]=as[1]; a.u[2]=as[2]; a.u[3]=as[3];
                if (valid) {
                    uint4 q = *(const uint4*)(pp2 + s*8);
                    bf.u[0]=q.x; bf.u[1]=q.y; bf.u[2]=q.z; bf.u[3]=q.w;
                } else {
                    bf.u[0]=0u; bf.u[1]=0u; bf.u[2]=0u; bf.u[3]=0u;
                }
                accp = __builtin_amdgcn_mfma_f32_32x32x16_bf16(a.s, bf.s, accp, 0, 0, 0);
            }
        }
        #pragma unroll
        for (int r = 0; r < 16; r++) {
            int oc = (r & 3) + 8*(r >> 2) + 4*bhalf;
            LF[w*1024 + oc*32 + pixl] = accp[r];
        }
    }
    __syncthreads();
    // reduce 4 partials + bias; sigmoid mask channels; result in LF[oc*32+px]
    #pragma unroll
    for (int k = 0; k < 4; k++) {
        int e = t + 256*k;
        int oc = e >> 5;
        float v = LF[e] + LF[1024+e] + LF[2048+e] + LF[3072+e];
        if (oc < 27) {
            v += ob[oc];
            if (oc >= 18) v = 1.f/(1.f+__expf(-v));
        }
        LF[e] = v;
    }
    __syncthreads();

    // ---- phase B: bilinear params for all 9 taps (pred from LDS) ----
    for (int it = t; it < 288; it += 256) {
        int tap = it >> 5, px = it & 31;
        int pix = pix0 + px;
        int h = pix / WID, wq = pix % WID;
        float dy = LF[(2*tap)*32 + px];
        float dx = LF[(2*tap+1)*32 + px];
        float mk = LF[(18+tap)*32 + px];
        float pyf = (float)(h - 1 + tap/3) + dy;
        float pxf = (float)(wq - 1 + tap%3) + dx;
        float y0f = floorf(pyf), x0f = floorf(pxf);
        float wy1 = pyf - y0f, wx1 = pxf - x0f;
        int iy0 = (int)y0f, ix0 = (int)x0f;
        int iy1 = iy0 + 1,  ix1 = ix0 + 1;
        float vy0 = (iy0 >= 0 && iy0 < HGT) ? 1.f : 0.f;
        float vy1 = (iy1 >= 0 && iy1 < HGT) ? 1.f : 0.f;
        float vx0 = (ix0 >= 0 && ix0 < WID) ? 1.f : 0.f;
        float vx1 = (ix1 >= 0 && ix1 < WID) ? 1.f : 0.f;
        int cy0 = min(max(iy0,0),HGT-1), cy1 = min(max(iy1,0),HGT-1);
        int cx0 = min(max(ix0,0),WID-1), cx1 = min(max(ix1,0),WID-1);
        int base = (tap*32 + px)*4;
        sidx9[base+0] = cy0*WID+cx0; sidx9[base+1] = cy0*WID+cx1;
        sidx9[base+2] = cy1*WID+cx0; sidx9[base+3] = cy1*WID+cx1;
        swgt9[base+0] = (1.f-wy1)*(1.f-wx1)*mk*vy0*vx0;
        swgt9[base+1] = (1.f-wy1)*wx1*mk*vy0*vx1;
        swgt9[base+2] = wy1*(1.f-wx1)*mk*vy1*vx0;
        swgt9[base+3] = wy1*wx1*mk*vy1*vx1;
    }
    __syncthreads();

    // ---- phase C: main dcn loop ----
    uint2  u[4][4];      // [pass][corner] gathered channel data (this lane's 4 ch)
    float4 W[4];         // [pass] bilinear weights
    uint2  samp[4];      // [pass] packed bf16x2 x2 sampled output

    // prologue gather+compute for tap 0
    #pragma unroll
    for (int p = 0; p < 4; p++) {
        int pix = w*8 + p*2 + pixoff;
        int base = (0*32 + pix)*4;
        int4 si = *(const int4*)&sidx9[base];
        W[p] = *(const float4*)&swgt9[base];
        u[p][0] = *(const uint2*)(yb + (size_t)si.x*64 + c4*2);
        u[p][1] = *(const uint2*)(yb + (size_t)si.y*64 + c4*2);
        u[p][2] = *(const uint2*)(yb + (size_t)si.z*64 + c4*2);
        u[p][3] = *(const uint2*)(yb + (size_t)si.w*64 + c4*2);
    }
    #pragma unroll
    for (int p = 0; p < 4; p++) {
        floatx2 W0, W1, W2, W3;
        W0.x = W0.y = W[p].x; W1.x = W1.y = W[p].y;
        W2.x = W2.y = W[p].z; W3.x = W3.y = W[p].w;
        floatx2 aX = up2(u[p][0].x) * W0;
        aX = __builtin_elementwise_fma(up2(u[p][1].x), W1, aX);
        aX = __builtin_elementwise_fma(up2(u[p][2].x), W2, aX);
        aX = __builtin_elementwise_fma(up2(u[p][3].x), W3, aX);
        floatx2 aY = up2(u[p][0].y) * W0;
        aY = __builtin_elementwise_fma(up2(u[p][1].y), W1, aY);
        aY = __builtin_elementwise_fma(up2(u[p][2].y), W2, aY);
        aY = __builtin_elementwise_fma(up2(u[p][3].y), W3, aY);
        samp[p].x = pk2(aX); samp[p].y = pk2(aY);
    }

    #pragma unroll
    for (int tap = 0; tap < 9; tap++) {
        uint32_t* S = &S2[tap & 1][0];
        #pragma unroll
        for (int p = 0; p < 4; p++) {
            int pix = w*8 + p*2 + pixoff;
            *(uint2*)&S[pix*S2R + c4*2] = samp[p];
        }
        __syncthreads();
        if (tap < 8) {
            #pragma unroll
            for (int p = 0; p < 4; p++) {
                int pix = w*8 + p*2 + pixoff;
                int base = ((tap+1)*32 + pix)*4;
                int4 si = *(const int4*)&sidx9[base];
                W[p] = *(const float4*)&swgt9[base];
                u[p][0] = *(const uint2*)(yb + (size_t)si.x*64 + c4*2);
                u[p][1] = *(const uint2*)(yb + (size_t)si.y*64 + c4*2);
                u[p][2] = *(const uint2*)(yb + (size_t)si.z*64 + c4*2);
                u[p][3] = *(const uint2*)(yb + (size_t)si.w*64 + c4*2);
            }
        }
        const uint32_t* wp = wpk + (size_t)((w*9 + tap)*8)*256 + lane*4;
        #pragma unroll
        for (int s = 0; s < 8; s++) {
            U8 a, bf;
            const uint32_t* wps = wp + s*256;
            a.u[0] = wps[0]; a.u[1] = wps[1]; a.u[2] = wps[2]; a.u[3] = wps[3];
            uint4 q = *(const uint4*)&S[pixl*S2R + s*8 + bhalf*4];
            bf.u[0]=q.x; bf.u[1]=q.y; bf.u[2]=q.z; bf.u[3]=q.w;
            acc = __builtin_amdgcn_mfma_f32_32x32x16_bf16(a.s, bf.s, acc, 0, 0, 0);
        }
        if (tap < 8) {
            #pragma unroll
            for (int p = 0; p < 4; p++) {
                floatx2 W0, W1, W2, W3;
                W0.x = W0.y = W[p].x; W1.x = W1.y = W[p].y;
                W2.x = W2.y = W[p].z; W3.x = W3.y = W[p].w;
                floatx2 aX = up2(u[p][0].x) * W0;
                aX = __builtin_elementwise_fma(up2(u[p][1].x), W1, aX);
                aX = __builtin_elementwise_fma(up2(u[p][2].x), W2, aX);
                aX = __builtin_elementwise_fma(up2(u[p][3].x), W3, aX);
                floatx2 aY = up2(u[p][0].y) * W0;
                aY = __builtin_elementwise_fma(up2(u[p][1].y), W1, aY);
                aY = __builtin_elementwise_fma(up2(u[p][2].y), W2, aY);
                aY = __builtin_elementwise_fma(up2(u[p][3].y), W3, aY);
                samp[p].x = pk2(aX); samp[p].y = pk2(aY);
            }
        }
    }
    // epilogue: BN2+SiLU into S2[1] (tap 8 consumed S2[0])
    uint32_t* SE = &S2[1][0];
    #pragma unroll
    for (int r = 0; r < 16; r += 2) {
        int oc = w*32 + (r & 3) + 8*(r >> 2) + 4*bhalf;
        float s0 = bn[256+oc],   be0 = bn[384+oc];
        float s1 = bn[256+oc+1], be1 = bn[384+oc+1];
        SE[pixl*S2R + (oc >> 1)] = pk2f(silu_f(acc[r]*s0+be0), silu_f(acc[r+1]*s1+be1));
    }
    __syncthreads();
    uint32_t* z2b = z2 + (size_t)b*HWX*64 + (size_t)pix0*64;
    int q2 = t & 31, p0 = t >> 5;
    #pragma unroll
    for (int pp = 0; pp < 4; pp++) {
        int pix = p0 + pp*8;
        uint2 v = *(const uint2*)&SE[pix*S2R + q2*2];
        *(uint2*)(z2b + (size_t)pix*64 + q2*2) = v;
    }
}

// ---------------- k4: conv1x1 (128->256, MFMA) + BN3 + SiLU + residual ----------------
// Round-0 body + batch->XCD swizzle: k4 reads Z2[b] on the XCD where k3 just
// wrote it (3.28 MB, L2-resident), and the two oc-halves sharing a Z2 window
// land on the same XCD.
__global__ __launch_bounds__(256) void k4_cv3(
    const uint32_t* __restrict__ z2, const uint32_t* __restrict__ wp3,
    const float* __restrict__ bn, const float* __restrict__ x, float* __restrict__ out)
{
    int i0 = blockIdx.x;                   // 1600
    int blk = (i0 & 7) * 200 + (i0 >> 3);  // bijective; XCD (i0%8) -> batch (i0&7)
    int half = blk & 1, blk2 = blk >> 1;
    int b = blk2 / 100, pix0 = (blk2 % 100) * 64;
    int t = threadIdx.x;
    int lane = t & 63, w = t >> 6;
    int pixl = lane & 31, bhalf = lane >> 5;
    int g = half*4 + w;
    floatx16 acc0 = {}, acc1 = {};
    const uint32_t* zb = z2 + (size_t)b*HWX*64 + (size_t)pix0*64;
    const uint32_t* wpg = wp3 + (size_t)(g*8)*256 + lane*4;

    #pragma unroll
    for (int s = 0; s < 8; s++) {
        U8 a, b0, b1;
        const uint32_t* as = wpg + s*256;
        a.u[0]=as[0]; a.u[1]=as[1]; a.u[2]=as[2]; a.u[3]=as[3];
        uint4 q0 = *(const uint4*)(zb + (size_t)pixl*64 + s*8 + bhalf*4);
        uint4 q1 = *(const uint4*)(zb + (size_t)(32+pixl)*64 + s*8 + bhalf*4);
        b0.u[0]=q0.x; b0.u[1]=q0.y; b0.u[2]=q0.z; b0.u[3]=q0.w;
        b1.u[0]=q1.x; b1.u[1]=q1.y; b1.u[2]=q1.z; b1.u[3]=q1.w;
        acc0 = __builtin_amdgcn_mfma_f32_32x32x16_bf16(a.s, b0.s, acc0, 0, 0, 0);
        acc1 = __builtin_amdgcn_mfma_f32_32x32x16_bf16(a.s, b1.s, acc1, 0, 0, 0);
    }
    const float* xb = x + (size_t)b*COUT*HWX + pix0;
    float* ob = out + (size_t)b*COUT*HWX + pix0;
    #pragma unroll
    for (int r = 0; r < 16; r++) {
        int oc = g*32 + (r & 3) + 8*(r >> 2) + 4*bhalf;
        float sc = bn[512+oc], be = bn[768+oc];
        float v0 = silu_f(acc0[r]*sc+be) + xb[(size_t)oc*HWX + pixl];
        float v1 = silu_f(acc1[r]*sc+be) + xb[(size_t)oc*HWX + 32 + pixl];
        ob[(size_t)oc*HWX + pixl]      = v0;
        ob[(size_t)oc*HWX + 32 + pixl] = v1;
    }
}

extern "C" void kernel_launch(void* const* d_in, const int* in_sizes, int n_in,
                              void* d_out, int out_size, void* d_ws, size_t ws_size,
                              hipStream_t stream) {
    const float* x     = (const float*)d_in[0];
    const float* cv1_w = (const float*)d_in[1];
    const float* bn1_g = (const float*)d_in[2];
    const float* bn1_b = (const float*)d_in[3];
    const float* bn1_m = (const float*)d_in[4];
    const float* bn1_v = (const float*)d_in[5];
    const float* off_w = (const float*)d_in[6];
    const float* off_b = (const float*)d_in[7];
    const float* dcn_w = (const float*)d_in[8];
    const float* dcn_b = (const float*)d_in[9];
    const float* bn2_g = (const float*)d_in[10];
    const float* bn2_b = (const float*)d_in[11];
    const float* bn2_m = (const float*)d_in[12];
    const float* bn2_v = (const float*)d_in[13];
    const float* cv3_w = (const float*)d_in[14];
    const float* bn3_g = (const float*)d_in[15];
    const float* bn3_b = (const float*)d_in[16];
    const float* bn3_m = (const float*)d_in[17];
    const float* bn3_v = (const float*)d_in[18];

    float* ws   = (float*)d_ws;
    float*    BN   = ws + WS_BN;
    uint32_t* Y2   = (uint32_t*)(ws + WS_Y2);
    uint32_t* Z2   = (uint32_t*)(ws + WS_Z2);
    uint32_t* WPK  = (uint32_t*)(ws + WS_WPK);
    uint32_t* WPO  = (uint32_t*)(ws + WS_WPO);
    uint32_t* WP1  = (uint32_t*)(ws + WS_WP1);
    uint32_t* WP3  = (uint32_t*)(ws + WS_WP3);

    hipLaunchKernelGGL(k0_prep, dim3(288), dim3(256), 0, stream,
        dcn_w, off_w, cv1_w, cv3_w,
        bn1_g, bn1_b, bn1_m, bn1_v,
        bn2_g, bn2_b, bn2_m, bn2_v, dcn_b,
        bn3_g, bn3_b, bn3_m, bn3_v, WPK, WPO, WP1, WP3, BN);
    hipLaunchKernelGGL(k1_cv1, dim3(800), dim3(256), 0, stream, x, WP1, BN, Y2);
    hipLaunchKernelGGL(k3_dcn, dim3(1600), dim3(256), 0, stream, Y2, WPO, off_b, WPK, BN, Z2);
    hipLaunchKernelGGL(k4_cv3, dim3(1600), dim3(256), 0, stream, Z2, WP3, BN, x, (float*)d_out);
}

// Round 9
// 221.564 us; speedup vs baseline: 1.0557x; 1.0488x over previous
//
#include <hip/hip_runtime.h>
#include <math.h>

// Problem constants
#define HWX   6400   // 80*80
#define WID   80
#define HGT   80
#define CMID  128
#define CIN   256
#define COUT  256

// Workspace layout (float/dword offsets)
#define WS_BN   0            // s1[128] b1[128] s2[128] b2[128] s3[256] b3[256] = 1024
#define WS_Y2   1024         // (8,6400,128) bf16 NHWC = 3,276,800 dwords
#define WS_Z2   3277824      // (8,6400,128) bf16 NHWC = 3,276,800 dwords
#define WS_WPK  6554624      // dcn_w prepacked A-frags: 73,728 dwords
#define WS_WPO  6628352      // off_w prepacked A-frags: 18,432 dwords
#define WS_WP1  6646784      // cv1_w prepacked A-frags: 16,384 dwords
#define WS_WP3  6663168      // cv3_w prepacked A-frags: 16,384 dwords

typedef float floatx16 __attribute__((ext_vector_type(16)));
typedef short shortx8  __attribute__((ext_vector_type(8)));
typedef float floatx2  __attribute__((ext_vector_type(2)));

union U8 { uint32_t u[4]; shortx8 s; };

__device__ __forceinline__ float silu_f(float t){ return t / (1.f + __expf(-t)); }
__device__ __forceinline__ uint32_t f2bf(float f){           // RNE fp32->bf16 (cold paths)
    uint32_t u = __float_as_uint(f);
    return (u + 0x7fffu + ((u >> 16) & 1u)) >> 16;
}
// unpack bf16x2 dword -> float2 (lo, hi)
__device__ __forceinline__ floatx2 up2(uint32_t u){
    floatx2 r; r.x = __uint_as_float(u << 16); r.y = __uint_as_float(u & 0xffff0000u); return r;
}
// pack float2 -> bf16x2 dword (round-half-up: +0x8000 then take high halves via v_perm)
__device__ __forceinline__ uint32_t pk2(floatx2 v){
    return __builtin_amdgcn_perm(__float_as_uint(v.y) + 0x8000u,
                                 __float_as_uint(v.x) + 0x8000u, 0x07060302u);
}
__device__ __forceinline__ uint32_t pk2f(float a, float b){ floatx2 v; v.x=a; v.y=b; return pk2(v); }

// 4-corner bilinear blend, 4 dwords (8 bf16 channels) wide
__device__ __forceinline__ uint4 blend4(uint4 u0, uint4 u1, uint4 u2, uint4 u3, float4 Wp){
    floatx2 W0, W1, W2, W3;
    W0.x = W0.y = Wp.x; W1.x = W1.y = Wp.y;
    W2.x = W2.y = Wp.z; W3.x = W3.y = Wp.w;
    uint4 r; floatx2 a;
    a = up2(u0.x)*W0;
    a = __builtin_elementwise_fma(up2(u1.x), W1, a);
    a = __builtin_elementwise_fma(up2(u2.x), W2, a);
    a = __builtin_elementwise_fma(up2(u3.x), W3, a); r.x = pk2(a);
    a = up2(u0.y)*W0;
    a = __builtin_elementwise_fma(up2(u1.y), W1, a);
    a = __builtin_elementwise_fma(up2(u2.y), W2, a);
    a = __builtin_elementwise_fma(up2(u3.y), W3, a); r.y = pk2(a);
    a = up2(u0.z)*W0;
    a = __builtin_elementwise_fma(up2(u1.z), W1, a);
    a = __builtin_elementwise_fma(up2(u2.z), W2, a);
    a = __builtin_elementwise_fma(up2(u3.z), W3, a); r.z = pk2(a);
    a = up2(u0.w)*W0;
    a = __builtin_elementwise_fma(up2(u1.w), W1, a);
    a = __builtin_elementwise_fma(up2(u2.w), W2, a);
    a = __builtin_elementwise_fma(up2(u3.w), W3, a); r.w = pk2(a);
    return r;
}

// ---------------- prep: BN fold + MFMA weight prepacks ----------------
// A-frag convention (verified): lane's oc = g*32 + (lane&31);
// k-index c = s*16 + (lane>>5)*8 + 2j (+1 in hi half of dword j).
__global__ __launch_bounds__(256) void k0_prep(
    const float* __restrict__ dcn_w, const float* __restrict__ off_w,
    const float* __restrict__ cv1_w, const float* __restrict__ cv3_w,
    const float* __restrict__ g1, const float* __restrict__ b1, const float* __restrict__ m1, const float* __restrict__ v1,
    const float* __restrict__ g2, const float* __restrict__ b2, const float* __restrict__ m2, const float* __restrict__ v2,
    const float* __restrict__ dcn_b,
    const float* __restrict__ g3, const float* __restrict__ b3, const float* __restrict__ m3, const float* __restrict__ v3,
    uint32_t* __restrict__ wpk, uint32_t* __restrict__ wpo,
    uint32_t* __restrict__ wp1, uint32_t* __restrict__ wp3, float* __restrict__ bnw)
{
    int i = blockIdx.x * 256 + threadIdx.x;
    if (i < 4*9*8*256) {                   // dcn_w: ((g*9+tap)*8+s)*256 + lane*4 + j
        int j = i & 3, lane = (i >> 2) & 63, s = (i >> 8) & 7;
        int r2 = i >> 11; int tap = r2 % 9, g = r2 / 9;
        int oc = g*32 + (lane & 31);
        int c  = s*16 + ((lane >> 5) << 3) + 2*j;
        wpk[i] = f2bf(dcn_w[(oc*128 + c)*9 + tap]) | (f2bf(dcn_w[(oc*128 + c + 1)*9 + tap]) << 16);
    }
    if (i < 9*8*256) {                     // off_w (27 oc pad 32): (tap*8+s)*256 + lane*4 + j
        int j = i & 3, lane = (i >> 2) & 63, s = (i >> 8) & 7, tap = i >> 11;
        int oc = lane & 31;
        int c  = s*16 + ((lane >> 5) << 3) + 2*j;
        float lo = (oc < 27) ? off_w[(oc*128 + c)*9 + tap] : 0.f;
        float hi = (oc < 27) ? off_w[(oc*128 + c + 1)*9 + tap] : 0.f;
        wpo[i] = f2bf(lo) | (f2bf(hi) << 16);
    }
    if (i < 4*16*256) {                    // cv1_w (128x256): (g*16+s)*256 + lane*4 + j
        int j = i & 3, lane = (i >> 2) & 63, s = (i >> 8) & 15, g = i >> 12;
        int oc = g*32 + (lane & 31);
        int c  = s*16 + ((lane >> 5) << 3) + 2*j;
        wp1[i] = f2bf(cv1_w[oc*256 + c]) | (f2bf(cv1_w[oc*256 + c + 1]) << 16);
    }
    if (i < 8*8*256) {                     // cv3_w (256x128): (g*8+s)*256 + lane*4 + j
        int j = i & 3, lane = (i >> 2) & 63, s = (i >> 8) & 7, g = i >> 11;
        int oc = g*32 + (lane & 31);
        int c  = s*16 + ((lane >> 5) << 3) + 2*j;
        wp3[i] = f2bf(cv3_w[oc*128 + c]) | (f2bf(cv3_w[oc*128 + c + 1]) << 16);
    }
    if (i < 128) {
        float inv = g1[i] * rsqrtf(v1[i] + 1e-5f);
        bnw[i] = inv; bnw[128+i] = b1[i] - m1[i]*inv;
    } else if (i < 256) {
        int j = i - 128;
        float inv = g2[j] * rsqrtf(v2[j] + 1e-5f);
        bnw[256+j] = inv; bnw[384+j] = b2[j] - m2[j]*inv + inv*dcn_b[j];  // fold dcn bias
    } else if (i < 512) {
        int j = i - 256;
        float inv = g3[j] * rsqrtf(v3[j] + 1e-5f);
        bnw[512+j] = inv; bnw[768+j] = b3[j] - m3[j]*inv;
    }
}

// ---------------- k1: conv1x1 (256->128, MFMA) + BN1 + SiLU -> Y2 bf16 NHWC ----------------
#define K1PAD 68
__global__ __launch_bounds__(256) void k1_cv1(
    const float* __restrict__ x, const uint32_t* __restrict__ wp1,
    const float* __restrict__ bn, uint32_t* __restrict__ y2)
{
    __shared__ __align__(16) uint32_t L[64*66];  // staging [0..16*68); epilogue transpose [64][66]
    int i0 = blockIdx.x;                   // 800
    int blk = (i0 & 7) * 100 + (i0 >> 3);  // bijective; XCD (i0%8) -> batch (i0&7)
    int b = blk / 100, pix0 = (blk % 100) * 64;
    int t = threadIdx.x;
    int lane = t & 63, w = t >> 6;
    int pixl = lane & 31, bhalf = lane >> 5;
    floatx16 acc0 = {}, acc1 = {};
    const float* xb = x + (size_t)b*CIN*HWX + pix0;
    const uint32_t* wpg = wp1 + (size_t)(w*16)*256 + lane*4;

    int r2 = t >> 4, c4 = (t & 15) * 4;    // staging: thread loads ch pair (2*r2,2*r2+1), 4 pix
    for (int kk = 0; kk < 256; kk += 32) {
        float4 a0 = *(const float4*)(xb + (size_t)(kk + 2*r2)*HWX + c4);
        float4 a1 = *(const float4*)(xb + (size_t)(kk + 2*r2 + 1)*HWX + c4);
        uint4 q;
        q.x = pk2f(a0.x, a1.x);
        q.y = pk2f(a0.y, a1.y);
        q.z = pk2f(a0.z, a1.z);
        q.w = pk2f(a0.w, a1.w);
        __syncthreads();                   // prev iter's frag reads done
        *(uint4*)&L[r2*K1PAD + c4] = q;
        __syncthreads();
        #pragma unroll
        for (int sl = 0; sl < 2; sl++) {
            int s = (kk >> 4) + sl;
            U8 a, b0, b1;
            const uint32_t* as = wpg + s*256;
            a.u[0]=as[0]; a.u[1]=as[1]; a.u[2]=as[2]; a.u[3]=as[3];
            int row = sl*8 + bhalf*4;
            #pragma unroll
            for (int j = 0; j < 4; j++) b0.u[j] = L[(row+j)*K1PAD + pixl];
            #pragma unroll
            for (int j = 0; j < 4; j++) b1.u[j] = L[(row+j)*K1PAD + 32 + pixl];
            acc0 = __builtin_amdgcn_mfma_f32_32x32x16_bf16(a.s, b0.s, acc0, 0, 0, 0);
            acc1 = __builtin_amdgcn_mfma_f32_32x32x16_bf16(a.s, b1.s, acc1, 0, 0, 0);
        }
    }
    __syncthreads();
    #pragma unroll
    for (int r = 0; r < 16; r += 2) {
        int oc = w*32 + (r & 3) + 8*(r >> 2) + 4*bhalf;      // even; pair (oc, oc+1)
        float s0 = bn[oc],   be0 = bn[128+oc];
        float s1 = bn[oc+1], be1 = bn[128+oc+1];
        uint32_t d0 = pk2f(silu_f(acc0[r]*s0+be0), silu_f(acc0[r+1]*s1+be1));
        uint32_t d1 = pk2f(silu_f(acc1[r]*s0+be0), silu_f(acc1[r+1]*s1+be1));
        int oc2 = oc >> 1;
        L[pixl*66 + oc2]        = d0;
        L[(32+pixl)*66 + oc2]   = d1;
    }
    __syncthreads();
    uint32_t* y2b = y2 + (size_t)b*HWX*64 + (size_t)pix0*64;
    int q2 = t & 31, p0 = t >> 5;
    #pragma unroll
    for (int pp = 0; pp < 8; pp++) {
        int pix = p0 + pp*8;
        uint2 v = make_uint2(L[pix*66 + q2*2], L[pix*66 + q2*2 + 1]);
        *(uint2*)(y2b + (size_t)pix*64 + q2*2) = v;
    }
}

// ---------------- k3: fused offset-conv + deformable conv (MFMA bf16) ----------------
// Round-5 structure (verified passing; gathers AFTER barrier — r7 proved the
// pre-barrier hoist regresses 33% via the vmcnt(0) barrier drain).
// THIS ROUND (single variable): gathers widened uint2 -> uint4. Lane map
// c8=lane&15 (8-ch slot), pg=lane>>4 (pixel group); one instruction fetches
// 4 pixel-corners (16B/lane) -> 8 gather instrs/wave/tap instead of 32, 4x
// less address VALU. LDS MFMA-side layout unchanged (ds_write_b128 at
// pix*68+c8*4, 16B-aligned since 68=4*17). Also isolates the uint4 map that
// was共 present in all r1-r4 failures but never tested alone.
#define S2R 68
__global__ __launch_bounds__(256) void k3_dcn(
    const uint32_t* __restrict__ y2, const uint32_t* __restrict__ wpo,
    const float* __restrict__ ob,
    const uint32_t* __restrict__ wpk, const float* __restrict__ bn, uint32_t* __restrict__ z2)
{
    __shared__ __align__(16) uint32_t S2[2][32*S2R];   // 17408 B (phase A reuses as 4x1024 fp32)
    __shared__ __align__(16) int   sidx9[9*32*4];      // 4608 B
    __shared__ __align__(16) float swgt9[9*32*4];      // 4608 B
    int i0 = blockIdx.x;                   // 1600
    int blk = (i0 & 7) * 200 + (i0 >> 3);  // bijective; XCD (i0%8) -> batch (i0&7)
    int b = blk / 200, pix0 = (blk % 200) * 32;
    int t = threadIdx.x;
    int lane = t & 63, w = t >> 6;
    int pixl = lane & 31, bhalf = lane >> 5;
    const uint32_t* yb = y2 + (size_t)b*HWX*64;
    floatx16 acc = {};
    float* LF = (float*)&S2[0][0];

    // ---- phase A: offset-conv pred partials (wave w: taps 2w..2w+1, wave3: 6..8) ----
    {
        floatx16 accp = {};
        int tap0 = (w < 3) ? w*2 : 6;
        int ntap = (w < 3) ? 2 : 3;
        int p = pix0 + pixl;
        int h = p / WID, xw = p % WID;
        for (int tt = 0; tt < ntap; tt++) {
            int tap = tap0 + tt;
            int gh = h + tap/3 - 1, gx = xw + tap%3 - 1;
            bool valid = (gh >= 0) && (gh < HGT) && (gx >= 0) && (gx < WID);
            const uint32_t* pp2 = yb + (size_t)(gh*WID + gx)*64 + bhalf*4;
            const uint32_t* ap = wpo + (size_t)(tap*8)*256 + lane*4;
            #pragma unroll
            for (int s = 0; s < 8; s++) {
                U8 a, bf;
                const uint32_t* as = ap + s*256;
                a.u[0]=as[0]; a.u[1]=as[1]; a.u[2]=as[2]; a.u[3]=as[3];
                if (valid) {
                    uint4 q = *(const uint4*)(pp2 + s*8);
                    bf.u[0]=q.x; bf.u[1]=q.y; bf.u[2]=q.z; bf.u[3]=q.w;
                } else {
                    bf.u[0]=0u; bf.u[1]=0u; bf.u[2]=0u; bf.u[3]=0u;
                }
                accp = __builtin_amdgcn_mfma_f32_32x32x16_bf16(a.s, bf.s, accp, 0, 0, 0);
            }
        }
        #pragma unroll
        for (int r = 0; r < 16; r++) {
            int oc = (r & 3) + 8*(r >> 2) + 4*bhalf;
            LF[w*1024 + oc*32 + pixl] = accp[r];
        }
    }
    __syncthreads();
    // reduce 4 partials + bias; sigmoid mask channels; result in LF[oc*32+px]
    #pragma unroll
    for (int k = 0; k < 4; k++) {
        int e = t + 256*k;
        int oc = e >> 5;
        float v = LF[e] + LF[1024+e] + LF[2048+e] + LF[3072+e];
        if (oc < 27) {
            v += ob[oc];
            if (oc >= 18) v = 1.f/(1.f+__expf(-v));
        }
        LF[e] = v;
    }
    __syncthreads();

    // ---- phase B: bilinear params for all 9 taps (pred from LDS) ----
    for (int it = t; it < 288; it += 256) {
        int tap = it >> 5, px = it & 31;
        int pix = pix0 + px;
        int h = pix / WID, wq = pix % WID;
        float dy = LF[(2*tap)*32 + px];
        float dx = LF[(2*tap+1)*32 + px];
        float mk = LF[(18+tap)*32 + px];
        float pyf = (float)(h - 1 + tap/3) + dy;
        float pxf = (float)(wq - 1 + tap%3) + dx;
        float y0f = floorf(pyf), x0f = floorf(pxf);
        float wy1 = pyf - y0f, wx1 = pxf - x0f;
        int iy0 = (int)y0f, ix0 = (int)x0f;
        int iy1 = iy0 + 1,  ix1 = ix0 + 1;
        float vy0 = (iy0 >= 0 && iy0 < HGT) ? 1.f : 0.f;
        float vy1 = (iy1 >= 0 && iy1 < HGT) ? 1.f : 0.f;
        float vx0 = (ix0 >= 0 && ix0 < WID) ? 1.f : 0.f;
        float vx1 = (ix1 >= 0 && ix1 < WID) ? 1.f : 0.f;
        int cy0 = min(max(iy0,0),HGT-1), cy1 = min(max(iy1,0),HGT-1);
        int cx0 = min(max(ix0,0),WID-1), cx1 = min(max(ix1,0),WID-1);
        int base = (tap*32 + px)*4;
        sidx9[base+0] = cy0*WID+cx0; sidx9[base+1] = cy0*WID+cx1;
        sidx9[base+2] = cy1*WID+cx0; sidx9[base+3] = cy1*WID+cx1;
        swgt9[base+0] = (1.f-wy1)*(1.f-wx1)*mk*vy0*vx0;
        swgt9[base+1] = (1.f-wy1)*wx1*mk*vy0*vx1;
        swgt9[base+2] = wy1*(1.f-wx1)*mk*vy1*vx0;
        swgt9[base+3] = wy1*wx1*mk*vy1*vx1;
    }
    __syncthreads();

    // ---- phase C: main dcn loop (uint4 gathers: 8 instrs/wave/tap) ----
    uint4  u[2][4];      // [pass][corner] gathered channel data (this lane's 8 ch)
    float4 W[2];         // [pass] bilinear weights
    uint4  samp[2];      // [pass] packed bf16x2 x4 sampled output
    int c8 = lane & 15, pg = lane >> 4;

    // prologue gather+compute for tap 0
    #pragma unroll
    for (int p = 0; p < 2; p++) {
        int pix = w*8 + p*4 + pg;
        int base = (0*32 + pix)*4;
        int4 si = *(const int4*)&sidx9[base];
        W[p] = *(const float4*)&swgt9[base];
        u[p][0] = *(const uint4*)(yb + (size_t)si.x*64 + c8*4);
        u[p][1] = *(const uint4*)(yb + (size_t)si.y*64 + c8*4);
        u[p][2] = *(const uint4*)(yb + (size_t)si.z*64 + c8*4);
        u[p][3] = *(const uint4*)(yb + (size_t)si.w*64 + c8*4);
    }
    #pragma unroll
    for (int p = 0; p < 2; p++)
        samp[p] = blend4(u[p][0], u[p][1], u[p][2], u[p][3], W[p]);

    #pragma unroll
    for (int tap = 0; tap < 9; tap++) {
        uint32_t* S = &S2[tap & 1][0];
        #pragma unroll
        for (int p = 0; p < 2; p++) {
            int pix = w*8 + p*4 + pg;
            *(uint4*)&S[pix*S2R + c8*4] = samp[p];
        }
        __syncthreads();
        if (tap < 8) {
            #pragma unroll
            for (int p = 0; p < 2; p++) {
                int pix = w*8 + p*4 + pg;
                int base = ((tap+1)*32 + pix)*4;
                int4 si = *(const int4*)&sidx9[base];
                W[p] = *(const float4*)&swgt9[base];
                u[p][0] = *(const uint4*)(yb + (size_t)si.x*64 + c8*4);
                u[p][1] = *(const uint4*)(yb + (size_t)si.y*64 + c8*4);
                u[p][2] = *(const uint4*)(yb + (size_t)si.z*64 + c8*4);
                u[p][3] = *(const uint4*)(yb + (size_t)si.w*64 + c8*4);
            }
        }
        const uint32_t* wp = wpk + (size_t)((w*9 + tap)*8)*256 + lane*4;
        #pragma unroll
        for (int s = 0; s < 8; s++) {
            U8 a, bf;
            const uint32_t* wps = wp + s*256;
            a.u[0] = wps[0]; a.u[1] = wps[1]; a.u[2] = wps[2]; a.u[3] = wps[3];
            uint4 q = *(const uint4*)&S[pixl*S2R + s*8 + bhalf*4];
            bf.u[0]=q.x; bf.u[1]=q.y; bf.u[2]=q.z; bf.u[3]=q.w;
            acc = __builtin_amdgcn_mfma_f32_32x32x16_bf16(a.s, bf.s, acc, 0, 0, 0);
        }
        if (tap < 8) {
            #pragma unroll
            for (int p = 0; p < 2; p++)
                samp[p] = blend4(u[p][0], u[p][1], u[p][2], u[p][3], W[p]);
        }
    }
    // epilogue: BN2+SiLU into S2[1] (tap 8 consumed S2[0])
    uint32_t* SE = &S2[1][0];
    #pragma unroll
    for (int r = 0; r < 16; r += 2) {
        int oc = w*32 + (r & 3) + 8*(r >> 2) + 4*bhalf;
        float s0 = bn[256+oc],   be0 = bn[384+oc];
        float s1 = bn[256+oc+1], be1 = bn[384+oc+1];
        SE[pixl*S2R + (oc >> 1)] = pk2f(silu_f(acc[r]*s0+be0), silu_f(acc[r+1]*s1+be1));
    }
    __syncthreads();
    uint32_t* z2b = z2 + (size_t)b*HWX*64 + (size_t)pix0*64;
    int q2 = t & 31, p0 = t >> 5;
    #pragma unroll
    for (int pp = 0; pp < 4; pp++) {
        int pix = p0 + pp*8;
        uint2 v = *(const uint2*)&SE[pix*S2R + q2*2];
        *(uint2*)(z2b + (size_t)pix*64 + q2*2) = v;
    }
}

// ---------------- k4: conv1x1 (128->256, MFMA) + BN3 + SiLU + residual ----------------
// Round-0 body + batch->XCD swizzle (kept from r8; neutral-to-positive).
__global__ __launch_bounds__(256) void k4_cv3(
    const uint32_t* __restrict__ z2, const uint32_t* __restrict__ wp3,
    const float* __restrict__ bn, const float* __restrict__ x, float* __restrict__ out)
{
    int i0 = blockIdx.x;                   // 1600
    int blk = (i0 & 7) * 200 + (i0 >> 3);  // bijective; XCD (i0%8) -> batch (i0&7)
    int half = blk & 1, blk2 = blk >> 1;
    int b = blk2 / 100, pix0 = (blk2 % 100) * 64;
    int t = threadIdx.x;
    int lane = t & 63, w = t >> 6;
    int pixl = lane & 31, bhalf = lane >> 5;
    int g = half*4 + w;
    floatx16 acc0 = {}, acc1 = {};
    const uint32_t* zb = z2 + (size_t)b*HWX*64 + (size_t)pix0*64;
    const uint32_t* wpg = wp3 + (size_t)(g*8)*256 + lane*4;

    #pragma unroll
    for (int s = 0; s < 8; s++) {
        U8 a, b0, b1;
        const uint32_t* as = wpg + s*256;
        a.u[0]=as[0]; a.u[1]=as[1]; a.u[2]=as[2]; a.u[3]=as[3];
        uint4 q0 = *(const uint4*)(zb + (size_t)pixl*64 + s*8 + bhalf*4);
        uint4 q1 = *(const uint4*)(zb + (size_t)(32+pixl)*64 + s*8 + bhalf*4);
        b0.u[0]=q0.x; b0.u[1]=q0.y; b0.u[2]=q0.z; b0.u[3]=q0.w;
        b1.u[0]=q1.x; b1.u[1]=q1.y; b1.u[2]=q1.z; b1.u[3]=q1.w;
        acc0 = __builtin_amdgcn_mfma_f32_32x32x16_bf16(a.s, b0.s, acc0, 0, 0, 0);
        acc1 = __builtin_amdgcn_mfma_f32_32x32x16_bf16(a.s, b1.s, acc1, 0, 0, 0);
    }
    const float* xb = x + (size_t)b*COUT*HWX + pix0;
    float* ob = out + (size_t)b*COUT*HWX + pix0;
    #pragma unroll
    for (int r = 0; r < 16; r++) {
        int oc = g*32 + (r & 3) + 8*(r >> 2) + 4*bhalf;
        float sc = bn[512+oc], be = bn[768+oc];
        float v0 = silu_f(acc0[r]*sc+be) + xb[(size_t)oc*HWX + pixl];
        float v1 = silu_f(acc1[r]*sc+be) + xb[(size_t)oc*HWX + 32 + pixl];
        ob[(size_t)oc*HWX + pixl]      = v0;
        ob[(size_t)oc*HWX + 32 + pixl] = v1;
    }
}

extern "C" void kernel_launch(void* const* d_in, const int* in_sizes, int n_in,
                              void* d_out, int out_size, void* d_ws, size_t ws_size,
                              hipStream_t stream) {
    const float* x     = (const float*)d_in[0];
    const float* cv1_w = (const float*)d_in[1];
    const float* bn1_g = (const float*)d_in[2];
    const float* bn1_b = (const float*)d_in[3];
    const float* bn1_m = (const float*)d_in[4];
    const float* bn1_v = (const float*)d_in[5];
    const float* off_w = (const float*)d_in[6];
    const float* off_b = (const float*)d_in[7];
    const float* dcn_w = (const float*)d_in[8];
    const float* dcn_b = (const float*)d_in[9];
    const float* bn2_g = (const float*)d_in[10];
    const float* bn2_b = (const float*)d_in[11];
    const float* bn2_m = (const float*)d_in[12];
    const float* bn2_v = (const float*)d_in[13];
    const float* cv3_w = (const float*)d_in[14];
    const float* bn3_g = (const float*)d_in[15];
    const float* bn3_b = (const float*)d_in[16];
    const float* bn3_m = (const float*)d_in[17];
    const float* bn3_v = (const float*)d_in[18];

    float* ws   = (float*)d_ws;
    float*    BN   = ws + WS_BN;
    uint32_t* Y2   = (uint32_t*)(ws + WS_Y2);
    uint32_t* Z2   = (uint32_t*)(ws + WS_Z2);
    uint32_t* WPK  = (uint32_t*)(ws + WS_WPK);
    uint32_t* WPO  = (uint32_t*)(ws + WS_WPO);
    uint32_t* WP1  = (uint32_t*)(ws + WS_WP1);
    uint32_t* WP3  = (uint32_t*)(ws + WS_WP3);

    hipLaunchKernelGGL(k0_prep, dim3(288), dim3(256), 0, stream,
        dcn_w, off_w, cv1_w, cv3_w,
        bn1_g, bn1_b, bn1_m, bn1_v,
        bn2_g, bn2_b, bn2_m, bn2_v, dcn_b,
        bn3_g, bn3_b, bn3_m, bn3_v, WPK, WPO, WP1, WP3, BN);
    hipLaunchKernelGGL(k1_cv1, dim3(800), dim3(256), 0, stream, x, WP1, BN, Y2);
    hipLaunchKernelGGL(k3_dcn, dim3(1600), dim3(256), 0, stream, Y2, WPO, off_b, WPK, BN, Z2);
    hipLaunchKernelGGL(k4_cv3, dim3(1600), dim3(256), 0, stream, Z2, WP3, BN, x, (float*)d_out);
}

// Round 10
// 220.835 us; speedup vs baseline: 1.0592x; 1.0033x over previous
//
#include <hip/hip_runtime.h>
#include <math.h>

// Problem constants
#define HWX   6400   // 80*80
#define WID   80
#define HGT   80
#define CMID  128
#define CIN   256
#define COUT  256

// Workspace layout (float/dword offsets)
#define WS_BN   0            // s1[128] b1[128] s2[128] b2[128] s3[256] b3[256] = 1024
#define WS_Y2   1024         // (8,6400,128) bf16 NHWC = 3,276,800 dwords
#define WS_Z2   3277824      // (8,6400,128) bf16 NHWC = 3,276,800 dwords
#define WS_WPK  6554624      // dcn_w prepacked A-frags: 73,728 dwords
#define WS_WPO  6628352      // off_w prepacked A-frags: 18,432 dwords
#define WS_WP1  6646784      // cv1_w prepacked A-frags: 16,384 dwords
#define WS_WP3  6663168      // cv3_w prepacked A-frags: 16,384 dwords

typedef float floatx16 __attribute__((ext_vector_type(16)));
typedef short shortx8  __attribute__((ext_vector_type(8)));
typedef float floatx2  __attribute__((ext_vector_type(2)));

union U8 { uint32_t u[4]; shortx8 s; };

__device__ __forceinline__ float silu_f(float t){ return t / (1.f + __expf(-t)); }
__device__ __forceinline__ uint32_t f2bf(float f){           // RNE fp32->bf16 (cold paths)
    uint32_t u = __float_as_uint(f);
    return (u + 0x7fffu + ((u >> 16) & 1u)) >> 16;
}
// unpack bf16x2 dword -> float2 (lo, hi)
__device__ __forceinline__ floatx2 up2(uint32_t u){
    floatx2 r; r.x = __uint_as_float(u << 16); r.y = __uint_as_float(u & 0xffff0000u); return r;
}
// pack float2 -> bf16x2 dword (round-half-up: +0x8000 then take high halves via v_perm)
__device__ __forceinline__ uint32_t pk2(floatx2 v){
    return __builtin_amdgcn_perm(__float_as_uint(v.y) + 0x8000u,
                                 __float_as_uint(v.x) + 0x8000u, 0x07060302u);
}
__device__ __forceinline__ uint32_t pk2f(float a, float b){ floatx2 v; v.x=a; v.y=b; return pk2(v); }

// 4-corner bilinear blend, 4 dwords (8 bf16 channels) wide
__device__ __forceinline__ uint4 blend4(uint4 u0, uint4 u1, uint4 u2, uint4 u3, float4 Wp){
    floatx2 W0, W1, W2, W3;
    W0.x = W0.y = Wp.x; W1.x = W1.y = Wp.y;
    W2.x = W2.y = Wp.z; W3.x = W3.y = Wp.w;
    uint4 r; floatx2 a;
    a = up2(u0.x)*W0;
    a = __builtin_elementwise_fma(up2(u1.x), W1, a);
    a = __builtin_elementwise_fma(up2(u2.x), W2, a);
    a = __builtin_elementwise_fma(up2(u3.x), W3, a); r.x = pk2(a);
    a = up2(u0.y)*W0;
    a = __builtin_elementwise_fma(up2(u1.y), W1, a);
    a = __builtin_elementwise_fma(up2(u2.y), W2, a);
    a = __builtin_elementwise_fma(up2(u3.y), W3, a); r.y = pk2(a);
    a = up2(u0.z)*W0;
    a = __builtin_elementwise_fma(up2(u1.z), W1, a);
    a = __builtin_elementwise_fma(up2(u2.z), W2, a);
    a = __builtin_elementwise_fma(up2(u3.z), W3, a); r.z = pk2(a);
    a = up2(u0.w)*W0;
    a = __builtin_elementwise_fma(up2(u1.w), W1, a);
    a = __builtin_elementwise_fma(up2(u2.w), W2, a);
    a = __builtin_elementwise_fma(up2(u3.w), W3, a); r.w = pk2(a);
    return r;
}

// ---------------- prep: BN fold + MFMA weight prepacks ----------------
// A-frag convention (verified): lane's oc = g*32 + (lane&31);
// k-index c = s*16 + (lane>>5)*8 + 2j (+1 in hi half of dword j).
__global__ __launch_bounds__(256) void k0_prep(
    const float* __restrict__ dcn_w, const float* __restrict__ off_w,
    const float* __restrict__ cv1_w, const float* __restrict__ cv3_w,
    const float* __restrict__ g1, const float* __restrict__ b1, const float* __restrict__ m1, const float* __restrict__ v1,
    const float* __restrict__ g2, const float* __restrict__ b2, const float* __restrict__ m2, const float* __restrict__ v2,
    const float* __restrict__ dcn_b,
    const float* __restrict__ g3, const float* __restrict__ b3, const float* __restrict__ m3, const float* __restrict__ v3,
    uint32_t* __restrict__ wpk, uint32_t* __restrict__ wpo,
    uint32_t* __restrict__ wp1, uint32_t* __restrict__ wp3, float* __restrict__ bnw)
{
    int i = blockIdx.x * 256 + threadIdx.x;
    if (i < 4*9*8*256) {                   // dcn_w: ((g*9+tap)*8+s)*256 + lane*4 + j
        int j = i & 3, lane = (i >> 2) & 63, s = (i >> 8) & 7;
        int r2 = i >> 11; int tap = r2 % 9, g = r2 / 9;
        int oc = g*32 + (lane & 31);
        int c  = s*16 + ((lane >> 5) << 3) + 2*j;
        wpk[i] = f2bf(dcn_w[(oc*128 + c)*9 + tap]) | (f2bf(dcn_w[(oc*128 + c + 1)*9 + tap]) << 16);
    }
    if (i < 9*8*256) {                     // off_w (27 oc pad 32): (tap*8+s)*256 + lane*4 + j
        int j = i & 3, lane = (i >> 2) & 63, s = (i >> 8) & 7, tap = i >> 11;
        int oc = lane & 31;
        int c  = s*16 + ((lane >> 5) << 3) + 2*j;
        float lo = (oc < 27) ? off_w[(oc*128 + c)*9 + tap] : 0.f;
        float hi = (oc < 27) ? off_w[(oc*128 + c + 1)*9 + tap] : 0.f;
        wpo[i] = f2bf(lo) | (f2bf(hi) << 16);
    }
    if (i < 4*16*256) {                    // cv1_w (128x256): (g*16+s)*256 + lane*4 + j
        int j = i & 3, lane = (i >> 2) & 63, s = (i >> 8) & 15, g = i >> 12;
        int oc = g*32 + (lane & 31);
        int c  = s*16 + ((lane >> 5) << 3) + 2*j;
        wp1[i] = f2bf(cv1_w[oc*256 + c]) | (f2bf(cv1_w[oc*256 + c + 1]) << 16);
    }
    if (i < 8*8*256) {                     // cv3_w (256x128): (g*8+s)*256 + lane*4 + j
        int j = i & 3, lane = (i >> 2) & 63, s = (i >> 8) & 7, g = i >> 11;
        int oc = g*32 + (lane & 31);
        int c  = s*16 + ((lane >> 5) << 3) + 2*j;
        wp3[i] = f2bf(cv3_w[oc*128 + c]) | (f2bf(cv3_w[oc*128 + c + 1]) << 16);
    }
    if (i < 128) {
        float inv = g1[i] * rsqrtf(v1[i] + 1e-5f);
        bnw[i] = inv; bnw[128+i] = b1[i] - m1[i]*inv;
    } else if (i < 256) {
        int j = i - 128;
        float inv = g2[j] * rsqrtf(v2[j] + 1e-5f);
        bnw[256+j] = inv; bnw[384+j] = b2[j] - m2[j]*inv + inv*dcn_b[j];  // fold dcn bias
    } else if (i < 512) {
        int j = i - 256;
        float inv = g3[j] * rsqrtf(v3[j] + 1e-5f);
        bnw[512+j] = inv; bnw[768+j] = b3[j] - m3[j]*inv;
    }
}

// ---------------- k1: conv1x1 (256->128, MFMA) + BN1 + SiLU -> Y2 bf16 NHWC ----------------
#define K1PAD 68
__global__ __launch_bounds__(256) void k1_cv1(
    const float* __restrict__ x, const uint32_t* __restrict__ wp1,
    const float* __restrict__ bn, uint32_t* __restrict__ y2)
{
    __shared__ __align__(16) uint32_t L[64*66];  // staging [0..16*68); epilogue transpose [64][66]
    int i0 = blockIdx.x;                   // 800
    int blk = (i0 & 7) * 100 + (i0 >> 3);  // bijective; XCD (i0%8) -> batch (i0&7)
    int b = blk / 100, pix0 = (blk % 100) * 64;
    int t = threadIdx.x;
    int lane = t & 63, w = t >> 6;
    int pixl = lane & 31, bhalf = lane >> 5;
    floatx16 acc0 = {}, acc1 = {};
    const float* xb = x + (size_t)b*CIN*HWX + pix0;
    const uint32_t* wpg = wp1 + (size_t)(w*16)*256 + lane*4;

    int r2 = t >> 4, c4 = (t & 15) * 4;    // staging: thread loads ch pair (2*r2,2*r2+1), 4 pix
    for (int kk = 0; kk < 256; kk += 32) {
        float4 a0 = *(const float4*)(xb + (size_t)(kk + 2*r2)*HWX + c4);
        float4 a1 = *(const float4*)(xb + (size_t)(kk + 2*r2 + 1)*HWX + c4);
        uint4 q;
        q.x = pk2f(a0.x, a1.x);
        q.y = pk2f(a0.y, a1.y);
        q.z = pk2f(a0.z, a1.z);
        q.w = pk2f(a0.w, a1.w);
        __syncthreads();                   // prev iter's frag reads done
        *(uint4*)&L[r2*K1PAD + c4] = q;
        __syncthreads();
        #pragma unroll
        for (int sl = 0; sl < 2; sl++) {
            int s = (kk >> 4) + sl;
            U8 a, b0, b1;
            const uint32_t* as = wpg + s*256;
            a.u[0]=as[0]; a.u[1]=as[1]; a.u[2]=as[2]; a.u[3]=as[3];
            int row = sl*8 + bhalf*4;
            #pragma unroll
            for (int j = 0; j < 4; j++) b0.u[j] = L[(row+j)*K1PAD + pixl];
            #pragma unroll
            for (int j = 0; j < 4; j++) b1.u[j] = L[(row+j)*K1PAD + 32 + pixl];
            acc0 = __builtin_amdgcn_mfma_f32_32x32x16_bf16(a.s, b0.s, acc0, 0, 0, 0);
            acc1 = __builtin_amdgcn_mfma_f32_32x32x16_bf16(a.s, b1.s, acc1, 0, 0, 0);
        }
    }
    __syncthreads();
    #pragma unroll
    for (int r = 0; r < 16; r += 2) {
        int oc = w*32 + (r & 3) + 8*(r >> 2) + 4*bhalf;      // even; pair (oc, oc+1)
        float s0 = bn[oc],   be0 = bn[128+oc];
        float s1 = bn[oc+1], be1 = bn[128+oc+1];
        uint32_t d0 = pk2f(silu_f(acc0[r]*s0+be0), silu_f(acc0[r+1]*s1+be1));
        uint32_t d1 = pk2f(silu_f(acc1[r]*s0+be0), silu_f(acc1[r+1]*s1+be1));
        int oc2 = oc >> 1;
        L[pixl*66 + oc2]        = d0;
        L[(32+pixl)*66 + oc2]   = d1;
    }
    __syncthreads();
    uint32_t* y2b = y2 + (size_t)b*HWX*64 + (size_t)pix0*64;
    int q2 = t & 31, p0 = t >> 5;
    #pragma unroll
    for (int pp = 0; pp < 8; pp++) {
        int pix = p0 + pp*8;
        uint2 v = make_uint2(L[pix*66 + q2*2], L[pix*66 + q2*2 + 1]);
        *(uint2*)(y2b + (size_t)pix*64 + q2*2) = v;
    }
}

// ---------------- k3: fused offset-conv + deformable conv (MFMA bf16) ----------------
// r9 base (uint4 gathers, XCD swizzle, gathers AFTER barrier) + THIS ROUND:
// 2 taps per barrier round. 4 LDS sample buffers (pairs P0={S2[0],S2[1]},
// P1={S2[2],S2[3]}); round r MFMAs taps {2r,2r+1} from pair r&1 while
// gathering taps {2r+2,2r+3} for pair (r+1)&1. Phase-C barriers 9 -> 5;
// 16 MFMAs + 16 gathers per round (2x MLP). Safety: writer of pair P at
// round r+1 is separated from round r-1's readers of P by the round-r
// barrier.
#define S2R 68
__global__ __launch_bounds__(256) void k3_dcn(
    const uint32_t* __restrict__ y2, const uint32_t* __restrict__ wpo,
    const float* __restrict__ ob,
    const uint32_t* __restrict__ wpk, const float* __restrict__ bn, uint32_t* __restrict__ z2)
{
    __shared__ __align__(16) uint32_t S2[4][32*S2R];   // 34816 B; phase A reuses S2[0..1] as 4x1024 fp32
    __shared__ __align__(16) int   sidx9[9*32*4];      // 4608 B
    __shared__ __align__(16) float swgt9[9*32*4];      // 4608 B
    int i0 = blockIdx.x;                   // 1600
    int blk = (i0 & 7) * 200 + (i0 >> 3);  // bijective; XCD (i0%8) -> batch (i0&7)
    int b = blk / 200, pix0 = (blk % 200) * 32;
    int t = threadIdx.x;
    int lane = t & 63, w = t >> 6;
    int pixl = lane & 31, bhalf = lane >> 5;
    const uint32_t* yb = y2 + (size_t)b*HWX*64;
    floatx16 acc = {};
    float* LF = (float*)&S2[0][0];

    // ---- phase A: offset-conv pred partials (wave w: taps 2w..2w+1, wave3: 6..8) ----
    {
        floatx16 accp = {};
        int tap0 = (w < 3) ? w*2 : 6;
        int ntap = (w < 3) ? 2 : 3;
        int p = pix0 + pixl;
        int h = p / WID, xw = p % WID;
        for (int tt = 0; tt < ntap; tt++) {
            int tap = tap0 + tt;
            int gh = h + tap/3 - 1, gx = xw + tap%3 - 1;
            bool valid = (gh >= 0) && (gh < HGT) && (gx >= 0) && (gx < WID);
            const uint32_t* pp2 = yb + (size_t)(gh*WID + gx)*64 + bhalf*4;
            const uint32_t* ap = wpo + (size_t)(tap*8)*256 + lane*4;
            #pragma unroll
            for (int s = 0; s < 8; s++) {
                U8 a, bf;
                const uint32_t* as = ap + s*256;
                a.u[0]=as[0]; a.u[1]=as[1]; a.u[2]=as[2]; a.u[3]=as[3];
                if (valid) {
                    uint4 q = *(const uint4*)(pp2 + s*8);
                    bf.u[0]=q.x; bf.u[1]=q.y; bf.u[2]=q.z; bf.u[3]=q.w;
                } else {
                    bf.u[0]=0u; bf.u[1]=0u; bf.u[2]=0u; bf.u[3]=0u;
                }
                accp = __builtin_amdgcn_mfma_f32_32x32x16_bf16(a.s, bf.s, accp, 0, 0, 0);
            }
        }
        #pragma unroll
        for (int r = 0; r < 16; r++) {
            int oc = (r & 3) + 8*(r >> 2) + 4*bhalf;
            LF[w*1024 + oc*32 + pixl] = accp[r];
        }
    }
    __syncthreads();
    // reduce 4 partials + bias; sigmoid mask channels; result in LF[oc*32+px]
    #pragma unroll
    for (int k = 0; k < 4; k++) {
        int e = t + 256*k;
        int oc = e >> 5;
        float v = LF[e] + LF[1024+e] + LF[2048+e] + LF[3072+e];
        if (oc < 27) {
            v += ob[oc];
            if (oc >= 18) v = 1.f/(1.f+__expf(-v));
        }
        LF[e] = v;
    }
    __syncthreads();

    // ---- phase B: bilinear params for all 9 taps (pred from LDS) ----
    for (int it = t; it < 288; it += 256) {
        int tap = it >> 5, px = it & 31;
        int pix = pix0 + px;
        int h = pix / WID, wq = pix % WID;
        float dy = LF[(2*tap)*32 + px];
        float dx = LF[(2*tap+1)*32 + px];
        float mk = LF[(18+tap)*32 + px];
        float pyf = (float)(h - 1 + tap/3) + dy;
        float pxf = (float)(wq - 1 + tap%3) + dx;
        float y0f = floorf(pyf), x0f = floorf(pxf);
        float wy1 = pyf - y0f, wx1 = pxf - x0f;
        int iy0 = (int)y0f, ix0 = (int)x0f;
        int iy1 = iy0 + 1,  ix1 = ix0 + 1;
        float vy0 = (iy0 >= 0 && iy0 < HGT) ? 1.f : 0.f;
        float vy1 = (iy1 >= 0 && iy1 < HGT) ? 1.f : 0.f;
        float vx0 = (ix0 >= 0 && ix0 < WID) ? 1.f : 0.f;
        float vx1 = (ix1 >= 0 && ix1 < WID) ? 1.f : 0.f;
        int cy0 = min(max(iy0,0),HGT-1), cy1 = min(max(iy1,0),HGT-1);
        int cx0 = min(max(ix0,0),WID-1), cx1 = min(max(ix1,0),WID-1);
        int base = (tap*32 + px)*4;
        sidx9[base+0] = cy0*WID+cx0; sidx9[base+1] = cy0*WID+cx1;
        sidx9[base+2] = cy1*WID+cx0; sidx9[base+3] = cy1*WID+cx1;
        swgt9[base+0] = (1.f-wy1)*(1.f-wx1)*mk*vy0*vx0;
        swgt9[base+1] = (1.f-wy1)*wx1*mk*vy0*vx1;
        swgt9[base+2] = wy1*(1.f-wx1)*mk*vy1*vx0;
        swgt9[base+3] = wy1*wx1*mk*vy1*vx1;
    }
    __syncthreads();

    // ---- phase C: 2-tap rounds ----
    uint4  u[4][4];      // [slot][corner]; slot = tp*2+p over 2 taps x 2 passes
    float4 W[4];
    uint4  samp[4];
    int c8 = lane & 15, pg = lane >> 4;

    // prologue: gather+blend taps 0,1
    #pragma unroll
    for (int i = 0; i < 4; i++) {
        int tp = i >> 1, p = i & 1;
        int pix = w*8 + p*4 + pg;
        int base = (tp*32 + pix)*4;
        int4 si = *(const int4*)&sidx9[base];
        W[i] = *(const float4*)&swgt9[base];
        u[i][0] = *(const uint4*)(yb + (size_t)si.x*64 + c8*4);
        u[i][1] = *(const uint4*)(yb + (size_t)si.y*64 + c8*4);
        u[i][2] = *(const uint4*)(yb + (size_t)si.z*64 + c8*4);
        u[i][3] = *(const uint4*)(yb + (size_t)si.w*64 + c8*4);
    }
    #pragma unroll
    for (int i = 0; i < 4; i++)
        samp[i] = blend4(u[i][0], u[i][1], u[i][2], u[i][3], W[i]);

    #pragma unroll
    for (int r = 0; r < 5; r++) {
        // write samp (taps 2r, 2r+1) into pair r&1
        #pragma unroll
        for (int i = 0; i < 4; i++) {
            int tp = i >> 1, p = i & 1;
            if (2*r + tp < 9) {
                int pix = w*8 + p*4 + pg;
                *(uint4*)&S2[(r & 1)*2 + tp][pix*S2R + c8*4] = samp[i];
            }
        }
        __syncthreads();
        if (r < 4) {                       // gather taps 2r+2, 2r+3 (AFTER barrier)
            #pragma unroll
            for (int i = 0; i < 4; i++) {
                int tp = i >> 1, p = i & 1;
                int tap = 2*r + 2 + tp;
                if (tap < 9) {
                    int pix = w*8 + p*4 + pg;
                    int base = (tap*32 + pix)*4;
                    int4 si = *(const int4*)&sidx9[base];
                    W[i] = *(const float4*)&swgt9[base];
                    u[i][0] = *(const uint4*)(yb + (size_t)si.x*64 + c8*4);
                    u[i][1] = *(const uint4*)(yb + (size_t)si.y*64 + c8*4);
                    u[i][2] = *(const uint4*)(yb + (size_t)si.z*64 + c8*4);
                    u[i][3] = *(const uint4*)(yb + (size_t)si.w*64 + c8*4);
                }
            }
        }
        #pragma unroll
        for (int tp = 0; tp < 2; tp++) {   // MFMA taps 2r, 2r+1
            int tap = 2*r + tp;
            if (tap < 9) {
                const uint32_t* wp = wpk + (size_t)((w*9 + tap)*8)*256 + lane*4;
                const uint32_t* Sb = &S2[(r & 1)*2 + tp][0];
                #pragma unroll
                for (int s = 0; s < 8; s++) {
                    U8 a, bf;
                    const uint32_t* wps = wp + s*256;
                    a.u[0] = wps[0]; a.u[1] = wps[1]; a.u[2] = wps[2]; a.u[3] = wps[3];
                    uint4 q = *(const uint4*)&Sb[pixl*S2R + s*8 + bhalf*4];
                    bf.u[0]=q.x; bf.u[1]=q.y; bf.u[2]=q.z; bf.u[3]=q.w;
                    acc = __builtin_amdgcn_mfma_f32_32x32x16_bf16(a.s, bf.s, acc, 0, 0, 0);
                }
            }
        }
        if (r < 4) {                       // blend taps 2r+2, 2r+3
            #pragma unroll
            for (int i = 0; i < 4; i++) {
                int tp = i >> 1;
                if (2*r + 2 + tp < 9)
                    samp[i] = blend4(u[i][0], u[i][1], u[i][2], u[i][3], W[i]);
            }
        }
    }
    // epilogue: BN2+SiLU into S2[1] (tap 8 consumed S2[0]; S2[1] last read
    // at round 2, several barriers back)
    uint32_t* SE = &S2[1][0];
    #pragma unroll
    for (int r = 0; r < 16; r += 2) {
        int oc = w*32 + (r & 3) + 8*(r >> 2) + 4*bhalf;
        float s0 = bn[256+oc],   be0 = bn[384+oc];
        float s1 = bn[256+oc+1], be1 = bn[384+oc+1];
        SE[pixl*S2R + (oc >> 1)] = pk2f(silu_f(acc[r]*s0+be0), silu_f(acc[r+1]*s1+be1));
    }
    __syncthreads();
    uint32_t* z2b = z2 + (size_t)b*HWX*64 + (size_t)pix0*64;
    int q2 = t & 31, p0 = t >> 5;
    #pragma unroll
    for (int pp = 0; pp < 4; pp++) {
        int pix = p0 + pp*8;
        uint2 v = *(const uint2*)&SE[pix*S2R + q2*2];
        *(uint2*)(z2b + (size_t)pix*64 + q2*2) = v;
    }
}

// ---------------- k4: conv1x1 (128->256, MFMA) + BN3 + SiLU + residual ----------------
// Round-0 body + batch->XCD swizzle (kept from r8; neutral-to-positive).
__global__ __launch_bounds__(256) void k4_cv3(
    const uint32_t* __restrict__ z2, const uint32_t* __restrict__ wp3,
    const float* __restrict__ bn, const float* __restrict__ x, float* __restrict__ out)
{
    int i0 = blockIdx.x;                   // 1600
    int blk = (i0 & 7) * 200 + (i0 >> 3);  // bijective; XCD (i0%8) -> batch (i0&7)
    int half = blk & 1, blk2 = blk >> 1;
    int b = blk2 / 100, pix0 = (blk2 % 100) * 64;
    int t = threadIdx.x;
    int lane = t & 63, w = t >> 6;
    int pixl = lane & 31, bhalf = lane >> 5;
    int g = half*4 + w;
    floatx16 acc0 = {}, acc1 = {};
    const uint32_t* zb = z2 + (size_t)b*HWX*64 + (size_t)pix0*64;
    const uint32_t* wpg = wp3 + (size_t)(g*8)*256 + lane*4;

    #pragma unroll
    for (int s = 0; s < 8; s++) {
        U8 a, b0, b1;
        const uint32_t* as = wpg + s*256;
        a.u[0]=as[0]; a.u[1]=as[1]; a.u[2]=as[2]; a.u[3]=as[3];
        uint4 q0 = *(const uint4*)(zb + (size_t)pixl*64 + s*8 + bhalf*4);
        uint4 q1 = *(const uint4*)(zb + (size_t)(32+pixl)*64 + s*8 + bhalf*4);
        b0.u[0]=q0.x; b0.u[1]=q0.y; b0.u[2]=q0.z; b0.u[3]=q0.w;
        b1.u[0]=q1.x; b1.u[1]=q1.y; b1.u[2]=q1.z; b1.u[3]=q1.w;
        acc0 = __builtin_amdgcn_mfma_f32_32x32x16_bf16(a.s, b0.s, acc0, 0, 0, 0);
        acc1 = __builtin_amdgcn_mfma_f32_32x32x16_bf16(a.s, b1.s, acc1, 0, 0, 0);
    }
    const float* xb = x + (size_t)b*COUT*HWX + pix0;
    float* ob = out + (size_t)b*COUT*HWX + pix0;
    #pragma unroll
    for (int r = 0; r < 16; r++) {
        int oc = g*32 + (r & 3) + 8*(r >> 2) + 4*bhalf;
        float sc = bn[512+oc], be = bn[768+oc];
        float v0 = silu_f(acc0[r]*sc+be) + xb[(size_t)oc*HWX + pixl];
        float v1 = silu_f(acc1[r]*sc+be) + xb[(size_t)oc*HWX + 32 + pixl];
        ob[(size_t)oc*HWX + pixl]      = v0;
        ob[(size_t)oc*HWX + 32 + pixl] = v1;
    }
}

extern "C" void kernel_launch(void* const* d_in, const int* in_sizes, int n_in,
                              void* d_out, int out_size, void* d_ws, size_t ws_size,
                              hipStream_t stream) {
    const float* x     = (const float*)d_in[0];
    const float* cv1_w = (const float*)d_in[1];
    const float* bn1_g = (const float*)d_in[2];
    const float* bn1_b = (const float*)d_in[3];
    const float* bn1_m = (const float*)d_in[4];
    const float* bn1_v = (const float*)d_in[5];
    const float* off_w = (const float*)d_in[6];
    const float* off_b = (const float*)d_in[7];
    const float* dcn_w = (const float*)d_in[8];
    const float* dcn_b = (const float*)d_in[9];
    const float* bn2_g = (const float*)d_in[10];
    const float* bn2_b = (const float*)d_in[11];
    const float* bn2_m = (const float*)d_in[12];
    const float* bn2_v = (const float*)d_in[13];
    const float* cv3_w = (const float*)d_in[14];
    const float* bn3_g = (const float*)d_in[15];
    const float* bn3_b = (const float*)d_in[16];
    const float* bn3_m = (const float*)d_in[17];
    const float* bn3_v = (const float*)d_in[18];

    float* ws   = (float*)d_ws;
    float*    BN   = ws + WS_BN;
    uint32_t* Y2   = (uint32_t*)(ws + WS_Y2);
    uint32_t* Z2   = (uint32_t*)(ws + WS_Z2);
    uint32_t* WPK  = (uint32_t*)(ws + WS_WPK);
    uint32_t* WPO  = (uint32_t*)(ws + WS_WPO);
    uint32_t* WP1  = (uint32_t*)(ws + WS_WP1);
    uint32_t* WP3  = (uint32_t*)(ws + WS_WP3);

    hipLaunchKernelGGL(k0_prep, dim3(288), dim3(256), 0, stream,
        dcn_w, off_w, cv1_w, cv3_w,
        bn1_g, bn1_b, bn1_m, bn1_v,
        bn2_g, bn2_b, bn2_m, bn2_v, dcn_b,
        bn3_g, bn3_b, bn3_m, bn3_v, WPK, WPO, WP1, WP3, BN);
    hipLaunchKernelGGL(k1_cv1, dim3(800), dim3(256), 0, stream, x, WP1, BN, Y2);
    hipLaunchKernelGGL(k3_dcn, dim3(1600), dim3(256), 0, stream, Y2, WPO, off_b, WPK, BN, Z2);
    hipLaunchKernelGGL(k4_cv3, dim3(1600), dim3(256), 0, stream, Z2, WP3, BN, x, (float*)d_out);
}

// Round 11
// 207.832 us; speedup vs baseline: 1.1254x; 1.0626x over previous
//
#include <hip/hip_runtime.h>
#include <math.h>

// Problem constants
#define HWX   6400   // 80*80
#define WID   80
#define HGT   80
#define CMID  128
#define CIN   256
#define COUT  256

// Workspace layout (float/dword offsets)
#define WS_BN   0            // s1[128] b1[128] s2[128] b2[128] s3[256] b3[256] = 1024
#define WS_Y2   1024         // (8,6400,128) bf16 NHWC = 3,276,800 dwords
#define WS_Z2   3277824      // (unused after k3/k4 fusion; kept for layout stability)
#define WS_WPK  6554624      // dcn_w prepacked A-frags: 73,728 dwords
#define WS_WPO  6628352      // off_w prepacked A-frags: 18,432 dwords
#define WS_WP1  6646784      // cv1_w prepacked A-frags: 16,384 dwords
#define WS_WP3  6663168      // cv3_w prepacked A-frags: 16,384 dwords

typedef float floatx16 __attribute__((ext_vector_type(16)));
typedef short shortx8  __attribute__((ext_vector_type(8)));
typedef float floatx2  __attribute__((ext_vector_type(2)));

union U8 { uint32_t u[4]; shortx8 s; };

__device__ __forceinline__ float silu_f(float t){ return t / (1.f + __expf(-t)); }
__device__ __forceinline__ uint32_t f2bf(float f){           // RNE fp32->bf16 (cold paths)
    uint32_t u = __float_as_uint(f);
    return (u + 0x7fffu + ((u >> 16) & 1u)) >> 16;
}
// unpack bf16x2 dword -> float2 (lo, hi)
__device__ __forceinline__ floatx2 up2(uint32_t u){
    floatx2 r; r.x = __uint_as_float(u << 16); r.y = __uint_as_float(u & 0xffff0000u); return r;
}
// pack float2 -> bf16x2 dword (round-half-up: +0x8000 then take high halves via v_perm)
__device__ __forceinline__ uint32_t pk2(floatx2 v){
    return __builtin_amdgcn_perm(__float_as_uint(v.y) + 0x8000u,
                                 __float_as_uint(v.x) + 0x8000u, 0x07060302u);
}
__device__ __forceinline__ uint32_t pk2f(float a, float b){ floatx2 v; v.x=a; v.y=b; return pk2(v); }

// 4-corner bilinear blend, 4 dwords (8 bf16 channels) wide
__device__ __forceinline__ uint4 blend4(uint4 u0, uint4 u1, uint4 u2, uint4 u3, float4 Wp){
    floatx2 W0, W1, W2, W3;
    W0.x = W0.y = Wp.x; W1.x = W1.y = Wp.y;
    W2.x = W2.y = Wp.z; W3.x = W3.y = Wp.w;
    uint4 r; floatx2 a;
    a = up2(u0.x)*W0;
    a = __builtin_elementwise_fma(up2(u1.x), W1, a);
    a = __builtin_elementwise_fma(up2(u2.x), W2, a);
    a = __builtin_elementwise_fma(up2(u3.x), W3, a); r.x = pk2(a);
    a = up2(u0.y)*W0;
    a = __builtin_elementwise_fma(up2(u1.y), W1, a);
    a = __builtin_elementwise_fma(up2(u2.y), W2, a);
    a = __builtin_elementwise_fma(up2(u3.y), W3, a); r.y = pk2(a);
    a = up2(u0.z)*W0;
    a = __builtin_elementwise_fma(up2(u1.z), W1, a);
    a = __builtin_elementwise_fma(up2(u2.z), W2, a);
    a = __builtin_elementwise_fma(up2(u3.z), W3, a); r.z = pk2(a);
    a = up2(u0.w)*W0;
    a = __builtin_elementwise_fma(up2(u1.w), W1, a);
    a = __builtin_elementwise_fma(up2(u2.w), W2, a);
    a = __builtin_elementwise_fma(up2(u3.w), W3, a); r.w = pk2(a);
    return r;
}

// ---------------- prep: BN fold + MFMA weight prepacks ----------------
// A-frag convention (verified): lane's oc = g*32 + (lane&31);
// k-index c = s*16 + (lane>>5)*8 + 2j (+1 in hi half of dword j).
__global__ __launch_bounds__(256) void k0_prep(
    const float* __restrict__ dcn_w, const float* __restrict__ off_w,
    const float* __restrict__ cv1_w, const float* __restrict__ cv3_w,
    const float* __restrict__ g1, const float* __restrict__ b1, const float* __restrict__ m1, const float* __restrict__ v1,
    const float* __restrict__ g2, const float* __restrict__ b2, const float* __restrict__ m2, const float* __restrict__ v2,
    const float* __restrict__ dcn_b,
    const float* __restrict__ g3, const float* __restrict__ b3, const float* __restrict__ m3, const float* __restrict__ v3,
    uint32_t* __restrict__ wpk, uint32_t* __restrict__ wpo,
    uint32_t* __restrict__ wp1, uint32_t* __restrict__ wp3, float* __restrict__ bnw)
{
    int i = blockIdx.x * 256 + threadIdx.x;
    if (i < 4*9*8*256) {                   // dcn_w: ((g*9+tap)*8+s)*256 + lane*4 + j
        int j = i & 3, lane = (i >> 2) & 63, s = (i >> 8) & 7;
        int r2 = i >> 11; int tap = r2 % 9, g = r2 / 9;
        int oc = g*32 + (lane & 31);
        int c  = s*16 + ((lane >> 5) << 3) + 2*j;
        wpk[i] = f2bf(dcn_w[(oc*128 + c)*9 + tap]) | (f2bf(dcn_w[(oc*128 + c + 1)*9 + tap]) << 16);
    }
    if (i < 9*8*256) {                     // off_w (27 oc pad 32): (tap*8+s)*256 + lane*4 + j
        int j = i & 3, lane = (i >> 2) & 63, s = (i >> 8) & 7, tap = i >> 11;
        int oc = lane & 31;
        int c  = s*16 + ((lane >> 5) << 3) + 2*j;
        float lo = (oc < 27) ? off_w[(oc*128 + c)*9 + tap] : 0.f;
        float hi = (oc < 27) ? off_w[(oc*128 + c + 1)*9 + tap] : 0.f;
        wpo[i] = f2bf(lo) | (f2bf(hi) << 16);
    }
    if (i < 4*16*256) {                    // cv1_w (128x256): (g*16+s)*256 + lane*4 + j
        int j = i & 3, lane = (i >> 2) & 63, s = (i >> 8) & 15, g = i >> 12;
        int oc = g*32 + (lane & 31);
        int c  = s*16 + ((lane >> 5) << 3) + 2*j;
        wp1[i] = f2bf(cv1_w[oc*256 + c]) | (f2bf(cv1_w[oc*256 + c + 1]) << 16);
    }
    if (i < 8*8*256) {                     // cv3_w (256x128): (g*8+s)*256 + lane*4 + j
        int j = i & 3, lane = (i >> 2) & 63, s = (i >> 8) & 7, g = i >> 11;
        int oc = g*32 + (lane & 31);
        int c  = s*16 + ((lane >> 5) << 3) + 2*j;
        wp3[i] = f2bf(cv3_w[oc*128 + c]) | (f2bf(cv3_w[oc*128 + c + 1]) << 16);
    }
    if (i < 128) {
        float inv = g1[i] * rsqrtf(v1[i] + 1e-5f);
        bnw[i] = inv; bnw[128+i] = b1[i] - m1[i]*inv;
    } else if (i < 256) {
        int j = i - 128;
        float inv = g2[j] * rsqrtf(v2[j] + 1e-5f);
        bnw[256+j] = inv; bnw[384+j] = b2[j] - m2[j]*inv + inv*dcn_b[j];  // fold dcn bias
    } else if (i < 512) {
        int j = i - 256;
        float inv = g3[j] * rsqrtf(v3[j] + 1e-5f);
        bnw[512+j] = inv; bnw[768+j] = b3[j] - m3[j]*inv;
    }
}

// ---------------- k1: conv1x1 (256->128, MFMA) + BN1 + SiLU -> Y2 bf16 NHWC ----------------
#define K1PAD 68
__global__ __launch_bounds__(256) void k1_cv1(
    const float* __restrict__ x, const uint32_t* __restrict__ wp1,
    const float* __restrict__ bn, uint32_t* __restrict__ y2)
{
    __shared__ __align__(16) uint32_t L[64*66];  // staging [0..16*68); epilogue transpose [64][66]
    int i0 = blockIdx.x;                   // 800
    int blk = (i0 & 7) * 100 + (i0 >> 3);  // bijective; XCD (i0%8) -> batch (i0&7)
    int b = blk / 100, pix0 = (blk % 100) * 64;
    int t = threadIdx.x;
    int lane = t & 63, w = t >> 6;
    int pixl = lane & 31, bhalf = lane >> 5;
    floatx16 acc0 = {}, acc1 = {};
    const float* xb = x + (size_t)b*CIN*HWX + pix0;
    const uint32_t* wpg = wp1 + (size_t)(w*16)*256 + lane*4;

    int r2 = t >> 4, c4 = (t & 15) * 4;    // staging: thread loads ch pair (2*r2,2*r2+1), 4 pix
    for (int kk = 0; kk < 256; kk += 32) {
        float4 a0 = *(const float4*)(xb + (size_t)(kk + 2*r2)*HWX + c4);
        float4 a1 = *(const float4*)(xb + (size_t)(kk + 2*r2 + 1)*HWX + c4);
        uint4 q;
        q.x = pk2f(a0.x, a1.x);
        q.y = pk2f(a0.y, a1.y);
        q.z = pk2f(a0.z, a1.z);
        q.w = pk2f(a0.w, a1.w);
        __syncthreads();                   // prev iter's frag reads done
        *(uint4*)&L[r2*K1PAD + c4] = q;
        __syncthreads();
        #pragma unroll
        for (int sl = 0; sl < 2; sl++) {
            int s = (kk >> 4) + sl;
            U8 a, b0, b1;
            const uint32_t* as = wpg + s*256;
            a.u[0]=as[0]; a.u[1]=as[1]; a.u[2]=as[2]; a.u[3]=as[3];
            int row = sl*8 + bhalf*4;
            #pragma unroll
            for (int j = 0; j < 4; j++) b0.u[j] = L[(row+j)*K1PAD + pixl];
            #pragma unroll
            for (int j = 0; j < 4; j++) b1.u[j] = L[(row+j)*K1PAD + 32 + pixl];
            acc0 = __builtin_amdgcn_mfma_f32_32x32x16_bf16(a.s, b0.s, acc0, 0, 0, 0);
            acc1 = __builtin_amdgcn_mfma_f32_32x32x16_bf16(a.s, b1.s, acc1, 0, 0, 0);
        }
    }
    __syncthreads();
    #pragma unroll
    for (int r = 0; r < 16; r += 2) {
        int oc = w*32 + (r & 3) + 8*(r >> 2) + 4*bhalf;      // even; pair (oc, oc+1)
        float s0 = bn[oc],   be0 = bn[128+oc];
        float s1 = bn[oc+1], be1 = bn[128+oc+1];
        uint32_t d0 = pk2f(silu_f(acc0[r]*s0+be0), silu_f(acc0[r+1]*s1+be1));
        uint32_t d1 = pk2f(silu_f(acc1[r]*s0+be0), silu_f(acc1[r+1]*s1+be1));
        int oc2 = oc >> 1;
        L[pixl*66 + oc2]        = d0;
        L[(32+pixl)*66 + oc2]   = d1;
    }
    __syncthreads();
    uint32_t* y2b = y2 + (size_t)b*HWX*64 + (size_t)pix0*64;
    int q2 = t & 31, p0 = t >> 5;
    #pragma unroll
    for (int pp = 0; pp < 8; pp++) {
        int pix = p0 + pp*8;
        uint2 v = make_uint2(L[pix*66 + q2*2], L[pix*66 + q2*2 + 1]);
        *(uint2*)(y2b + (size_t)pix*64 + q2*2) = v;
    }
}

// ---------------- k3: offset-conv + deformable conv + (FUSED) cv3 + BN3 + SiLU + residual ----------------
// Base = r9 phase A/B/C (uint4 gathers, single-tap double-buffer, gathers
// AFTER barrier, XCD batch swizzle; 26.6 KB LDS -> 3 blocks/CU — r10's 2-tap
// variant was a wash: +MLP paid for by -occupancy).
// NEW: cv3 (128->256) fused into the epilogue. SE holds exactly what k4 read
// from Z2 (same dword offsets, same bf16 values): B-frag = SE[pixl*68+s*8+
// bhalf*4]; each wave computes oc-groups {w, w+4} (2x16 acc), then BN3+SiLU+
// residual-add and stores the final output. Kills k4's launch + the Z2
// round-trip (13 MB write + 26 MB read). Numerics bit-identical.
#define S2R 68
__global__ __launch_bounds__(256) void k3_dcn(
    const uint32_t* __restrict__ y2, const uint32_t* __restrict__ wpo,
    const float* __restrict__ ob,
    const uint32_t* __restrict__ wpk, const float* __restrict__ bn,
    const uint32_t* __restrict__ wp3, const float* __restrict__ x,
    float* __restrict__ outp)
{
    __shared__ __align__(16) uint32_t S2[2][32*S2R];   // 17408 B (phase A reuses as 4x1024 fp32)
    __shared__ __align__(16) int   sidx9[9*32*4];      // 4608 B
    __shared__ __align__(16) float swgt9[9*32*4];      // 4608 B
    int i0 = blockIdx.x;                   // 1600
    int blk = (i0 & 7) * 200 + (i0 >> 3);  // bijective; XCD (i0%8) -> batch (i0&7)
    int b = blk / 200, pix0 = (blk % 200) * 32;
    int t = threadIdx.x;
    int lane = t & 63, w = t >> 6;
    int pixl = lane & 31, bhalf = lane >> 5;
    const uint32_t* yb = y2 + (size_t)b*HWX*64;
    floatx16 acc = {};
    float* LF = (float*)&S2[0][0];

    // ---- phase A: offset-conv pred partials (wave w: taps 2w..2w+1, wave3: 6..8) ----
    {
        floatx16 accp = {};
        int tap0 = (w < 3) ? w*2 : 6;
        int ntap = (w < 3) ? 2 : 3;
        int p = pix0 + pixl;
        int h = p / WID, xw = p % WID;
        for (int tt = 0; tt < ntap; tt++) {
            int tap = tap0 + tt;
            int gh = h + tap/3 - 1, gx = xw + tap%3 - 1;
            bool valid = (gh >= 0) && (gh < HGT) && (gx >= 0) && (gx < WID);
            const uint32_t* pp2 = yb + (size_t)(gh*WID + gx)*64 + bhalf*4;
            const uint32_t* ap = wpo + (size_t)(tap*8)*256 + lane*4;
            #pragma unroll
            for (int s = 0; s < 8; s++) {
                U8 a, bf;
                const uint32_t* as = ap + s*256;
                a.u[0]=as[0]; a.u[1]=as[1]; a.u[2]=as[2]; a.u[3]=as[3];
                if (valid) {
                    uint4 q = *(const uint4*)(pp2 + s*8);
                    bf.u[0]=q.x; bf.u[1]=q.y; bf.u[2]=q.z; bf.u[3]=q.w;
                } else {
                    bf.u[0]=0u; bf.u[1]=0u; bf.u[2]=0u; bf.u[3]=0u;
                }
                accp = __builtin_amdgcn_mfma_f32_32x32x16_bf16(a.s, bf.s, accp, 0, 0, 0);
            }
        }
        #pragma unroll
        for (int r = 0; r < 16; r++) {
            int oc = (r & 3) + 8*(r >> 2) + 4*bhalf;
            LF[w*1024 + oc*32 + pixl] = accp[r];
        }
    }
    __syncthreads();
    // reduce 4 partials + bias; sigmoid mask channels; result in LF[oc*32+px]
    #pragma unroll
    for (int k = 0; k < 4; k++) {
        int e = t + 256*k;
        int oc = e >> 5;
        float v = LF[e] + LF[1024+e] + LF[2048+e] + LF[3072+e];
        if (oc < 27) {
            v += ob[oc];
            if (oc >= 18) v = 1.f/(1.f+__expf(-v));
        }
        LF[e] = v;
    }
    __syncthreads();

    // ---- phase B: bilinear params for all 9 taps (pred from LDS) ----
    for (int it = t; it < 288; it += 256) {
        int tap = it >> 5, px = it & 31;
        int pix = pix0 + px;
        int h = pix / WID, wq = pix % WID;
        float dy = LF[(2*tap)*32 + px];
        float dx = LF[(2*tap+1)*32 + px];
        float mk = LF[(18+tap)*32 + px];
        float pyf = (float)(h - 1 + tap/3) + dy;
        float pxf = (float)(wq - 1 + tap%3) + dx;
        float y0f = floorf(pyf), x0f = floorf(pxf);
        float wy1 = pyf - y0f, wx1 = pxf - x0f;
        int iy0 = (int)y0f, ix0 = (int)x0f;
        int iy1 = iy0 + 1,  ix1 = ix0 + 1;
        float vy0 = (iy0 >= 0 && iy0 < HGT) ? 1.f : 0.f;
        float vy1 = (iy1 >= 0 && iy1 < HGT) ? 1.f : 0.f;
        float vx0 = (ix0 >= 0 && ix0 < WID) ? 1.f : 0.f;
        float vx1 = (ix1 >= 0 && ix1 < WID) ? 1.f : 0.f;
        int cy0 = min(max(iy0,0),HGT-1), cy1 = min(max(iy1,0),HGT-1);
        int cx0 = min(max(ix0,0),WID-1), cx1 = min(max(ix1,0),WID-1);
        int base = (tap*32 + px)*4;
        sidx9[base+0] = cy0*WID+cx0; sidx9[base+1] = cy0*WID+cx1;
        sidx9[base+2] = cy1*WID+cx0; sidx9[base+3] = cy1*WID+cx1;
        swgt9[base+0] = (1.f-wy1)*(1.f-wx1)*mk*vy0*vx0;
        swgt9[base+1] = (1.f-wy1)*wx1*mk*vy0*vx1;
        swgt9[base+2] = wy1*(1.f-wx1)*mk*vy1*vx0;
        swgt9[base+3] = wy1*wx1*mk*vy1*vx1;
    }
    __syncthreads();

    // ---- phase C: main dcn loop (uint4 gathers: 8 instrs/wave/tap) ----
    uint4  u[2][4];      // [pass][corner] gathered channel data (this lane's 8 ch)
    float4 W[2];         // [pass] bilinear weights
    uint4  samp[2];      // [pass] packed bf16x2 x4 sampled output
    int c8 = lane & 15, pg = lane >> 4;

    // prologue gather+compute for tap 0
    #pragma unroll
    for (int p = 0; p < 2; p++) {
        int pix = w*8 + p*4 + pg;
        int base = (0*32 + pix)*4;
        int4 si = *(const int4*)&sidx9[base];
        W[p] = *(const float4*)&swgt9[base];
        u[p][0] = *(const uint4*)(yb + (size_t)si.x*64 + c8*4);
        u[p][1] = *(const uint4*)(yb + (size_t)si.y*64 + c8*4);
        u[p][2] = *(const uint4*)(yb + (size_t)si.z*64 + c8*4);
        u[p][3] = *(const uint4*)(yb + (size_t)si.w*64 + c8*4);
    }
    #pragma unroll
    for (int p = 0; p < 2; p++)
        samp[p] = blend4(u[p][0], u[p][1], u[p][2], u[p][3], W[p]);

    #pragma unroll
    for (int tap = 0; tap < 9; tap++) {
        uint32_t* S = &S2[tap & 1][0];
        #pragma unroll
        for (int p = 0; p < 2; p++) {
            int pix = w*8 + p*4 + pg;
            *(uint4*)&S[pix*S2R + c8*4] = samp[p];
        }
        __syncthreads();
        if (tap < 8) {
            #pragma unroll
            for (int p = 0; p < 2; p++) {
                int pix = w*8 + p*4 + pg;
                int base = ((tap+1)*32 + pix)*4;
                int4 si = *(const int4*)&sidx9[base];
                W[p] = *(const float4*)&swgt9[base];
                u[p][0] = *(const uint4*)(yb + (size_t)si.x*64 + c8*4);
                u[p][1] = *(const uint4*)(yb + (size_t)si.y*64 + c8*4);
                u[p][2] = *(const uint4*)(yb + (size_t)si.z*64 + c8*4);
                u[p][3] = *(const uint4*)(yb + (size_t)si.w*64 + c8*4);
            }
        }
        const uint32_t* wp = wpk + (size_t)((w*9 + tap)*8)*256 + lane*4;
        #pragma unroll
        for (int s = 0; s < 8; s++) {
            U8 a, bf;
            const uint32_t* wps = wp + s*256;
            a.u[0] = wps[0]; a.u[1] = wps[1]; a.u[2] = wps[2]; a.u[3] = wps[3];
            uint4 q = *(const uint4*)&S[pixl*S2R + s*8 + bhalf*4];
            bf.u[0]=q.x; bf.u[1]=q.y; bf.u[2]=q.z; bf.u[3]=q.w;
            acc = __builtin_amdgcn_mfma_f32_32x32x16_bf16(a.s, bf.s, acc, 0, 0, 0);
        }
        if (tap < 8) {
            #pragma unroll
            for (int p = 0; p < 2; p++)
                samp[p] = blend4(u[p][0], u[p][1], u[p][2], u[p][3], W[p]);
        }
    }
    // BN2+SiLU into SE = S2[1] (tap 8 consumed S2[0]; S2[1] last read at tap 7,
    // separated by the tap-8 barrier)
    uint32_t* SE = &S2[1][0];
    #pragma unroll
    for (int r = 0; r < 16; r += 2) {
        int oc = w*32 + (r & 3) + 8*(r >> 2) + 4*bhalf;
        float s0 = bn[256+oc],   be0 = bn[384+oc];
        float s1 = bn[256+oc+1], be1 = bn[384+oc+1];
        SE[pixl*S2R + (oc >> 1)] = pk2f(silu_f(acc[r]*s0+be0), silu_f(acc[r+1]*s1+be1));
    }
    __syncthreads();

    // ---- fused cv3 (128->256) + BN3 + SiLU + residual ----
    // B-frag from SE (identical offsets/values to old k4's Z2 read).
    // Wave w computes oc-groups gA=w (oc w*32..), gB=w+4 (oc 128+w*32..).
    floatx16 c0 = {}, c1 = {};
    #pragma unroll
    for (int s = 0; s < 8; s++) {
        U8 a0, a1, bf;
        const uint32_t* w0 = wp3 + (size_t)(w*8 + s)*256 + lane*4;
        const uint32_t* w1 = wp3 + (size_t)((w+4)*8 + s)*256 + lane*4;
        a0.u[0]=w0[0]; a0.u[1]=w0[1]; a0.u[2]=w0[2]; a0.u[3]=w0[3];
        a1.u[0]=w1[0]; a1.u[1]=w1[1]; a1.u[2]=w1[2]; a1.u[3]=w1[3];
        uint4 q = *(const uint4*)&SE[pixl*S2R + s*8 + bhalf*4];
        bf.u[0]=q.x; bf.u[1]=q.y; bf.u[2]=q.z; bf.u[3]=q.w;
        c0 = __builtin_amdgcn_mfma_f32_32x32x16_bf16(a0.s, bf.s, c0, 0, 0, 0);
        c1 = __builtin_amdgcn_mfma_f32_32x32x16_bf16(a1.s, bf.s, c1, 0, 0, 0);
    }
    const float* xb = x + (size_t)b*COUT*HWX + pix0;
    float* obp = outp + (size_t)b*COUT*HWX + pix0;
    #pragma unroll
    for (int r = 0; r < 16; r++) {
        int ocl = (r & 3) + 8*(r >> 2) + 4*bhalf;
        int oc0 = w*32 + ocl;
        int oc1 = 128 + w*32 + ocl;
        float sc0 = bn[512+oc0], be0 = bn[768+oc0];
        float sc1 = bn[512+oc1], be1 = bn[768+oc1];
        float v0 = silu_f(c0[r]*sc0+be0) + xb[(size_t)oc0*HWX + pixl];
        float v1 = silu_f(c1[r]*sc1+be1) + xb[(size_t)oc1*HWX + pixl];
        obp[(size_t)oc0*HWX + pixl] = v0;
        obp[(size_t)oc1*HWX + pixl] = v1;
    }
}

extern "C" void kernel_launch(void* const* d_in, const int* in_sizes, int n_in,
                              void* d_out, int out_size, void* d_ws, size_t ws_size,
                              hipStream_t stream) {
    const float* x     = (const float*)d_in[0];
    const float* cv1_w = (const float*)d_in[1];
    const float* bn1_g = (const float*)d_in[2];
    const float* bn1_b = (const float*)d_in[3];
    const float* bn1_m = (const float*)d_in[4];
    const float* bn1_v = (const float*)d_in[5];
    const float* off_w = (const float*)d_in[6];
    const float* off_b = (const float*)d_in[7];
    const float* dcn_w = (const float*)d_in[8];
    const float* dcn_b = (const float*)d_in[9];
    const float* bn2_g = (const float*)d_in[10];
    const float* bn2_b = (const float*)d_in[11];
    const float* bn2_m = (const float*)d_in[12];
    const float* bn2_v = (const float*)d_in[13];
    const float* cv3_w = (const float*)d_in[14];
    const float* bn3_g = (const float*)d_in[15];
    const float* bn3_b = (const float*)d_in[16];
    const float* bn3_m = (const float*)d_in[17];
    const float* bn3_v = (const float*)d_in[18];

    float* ws   = (float*)d_ws;
    float*    BN   = ws + WS_BN;
    uint32_t* Y2   = (uint32_t*)(ws + WS_Y2);
    uint32_t* WPK  = (uint32_t*)(ws + WS_WPK);
    uint32_t* WPO  = (uint32_t*)(ws + WS_WPO);
    uint32_t* WP1  = (uint32_t*)(ws + WS_WP1);
    uint32_t* WP3  = (uint32_t*)(ws + WS_WP3);

    hipLaunchKernelGGL(k0_prep, dim3(288), dim3(256), 0, stream,
        dcn_w, off_w, cv1_w, cv3_w,
        bn1_g, bn1_b, bn1_m, bn1_v,
        bn2_g, bn2_b, bn2_m, bn2_v, dcn_b,
        bn3_g, bn3_b, bn3_m, bn3_v, WPK, WPO, WP1, WP3, BN);
    hipLaunchKernelGGL(k1_cv1, dim3(800), dim3(256), 0, stream, x, WP1, BN, Y2);
    hipLaunchKernelGGL(k3_dcn, dim3(1600), dim3(256), 0, stream,
        Y2, WPO, off_b, WPK, BN, WP3, x, (float*)d_out);
}